// Round 11
// baseline (999.053 us; speedup 1.0000x reference)
//
#include <hip/hip_runtime.h>
#include <math.h>

// Problem dims: B=32, T=512, F=16, H=64, NH=4, HD=16, L=2.  BT=16384.

__device__ __forceinline__ float sigf(float x){
    return 1.f / (1.f + __expf(-x));
}
__device__ __forceinline__ float tanhf_(float x){
    float xc = fminf(fmaxf(x, -15.f), 15.f);   // clamp: avoid inf/inf NaN
    float e = __expf(-2.f * xc);
    return (1.f - e) / (1.f + e);
}
__device__ __forceinline__ float eluf(float x){
    return x > 0.f ? x : (__expf(x) - 1.f);
}
__device__ __forceinline__ float wsum64(float v){
    #pragma unroll
    for (int o = 1; o < 64; o <<= 1) v += __shfl_xor(v, o, 64);
    return v;
}
__device__ __forceinline__ float wmax64(float v){
    #pragma unroll
    for (int o = 1; o < 64; o <<= 1) v = fmaxf(v, __shfl_xor(v, o, 64));
    return v;
}

// Barrier that waits only for LDS ops (NOT vmcnt) — global stores/loads stay
// in flight across it (__syncthreads would drain vmcnt(0)).
#define BARRIER_LGKM() do {                                    \
    asm volatile("s_waitcnt lgkmcnt(0)" ::: "memory");         \
    __builtin_amdgcn_s_barrier();                              \
} while(0)

// ---------------------------------------------------------------------------
// Kernel 1: VSN. One block = 32 positions, 256 threads.  (unchanged)
// ---------------------------------------------------------------------------
__global__ __launch_bounds__(256) void tft_vsn_kernel(
    const float* __restrict__ x,
    const float* __restrict__ ip_w, const float* __restrict__ ip_b,
    const float* __restrict__ vfc1w, const float* __restrict__ vfc1b,
    const float* __restrict__ vfc2w, const float* __restrict__ vfc2b,
    const float* __restrict__ vlng, const float* __restrict__ vlnb,
    const float* __restrict__ sfc1w, const float* __restrict__ sfc1b,
    const float* __restrict__ sfc2w, const float* __restrict__ sfc2b,
    const float* __restrict__ sskw, const float* __restrict__ sskb,
    const float* __restrict__ slng, const float* __restrict__ slnb,
    float* __restrict__ vsn_out)
{
    __shared__ __align__(16) float s_x[512];
    __shared__ __align__(16) float s_ipw[64];
    __shared__ __align__(16) float s_ipb[64];
    __shared__ __align__(16) float s_xp[32*65];
    __shared__ __align__(16) float s_W1[64*64];
    __shared__ __align__(16) float s_W2[64*128];
    __shared__ __align__(16) float s_Wsk[64*16];
    __shared__ __align__(16) float s_h[32*65];
    __shared__ __align__(16) float s_sel2[32*32];
    __shared__ __align__(16) float s_wsm[32*16];
    __shared__ __align__(16) float s_lng[64];
    __shared__ __align__(16) float s_lnb[64];
    __shared__ __align__(16) float s_b1[64];
    __shared__ __align__(16) float s_b2[128];

    const int tid  = threadIdx.x;
    const int pos0 = blockIdx.x * 32;
    const int m    = tid >> 3;
    const int g8   = tid & 7;
    const int j0   = g8 * 8;

    if (tid < 128) ((float4*)s_x)[tid] = *(const float4*)(x + pos0*16 + tid*4);
    if (tid < 64) { s_ipw[tid] = ip_w[tid]; s_ipb[tid] = ip_b[tid]; }
    __syncthreads();

    float accS[8];
    #pragma unroll
    for (int i = 0; i < 8; i++) accS[i] = 0.f;
    float accK0 = 0.f, accK1 = 0.f;

    for (int f = 0; f < 16; f++){
        {
            float xb = s_x[m*16 + f];
            #pragma unroll
            for (int i = 0; i < 8; i++)
                s_xp[m*65 + j0 + i] = xb * s_ipw[j0+i] + s_ipb[j0+i];
        }
        #pragma unroll
        for (int i = 0; i < 4; i++)
            ((float4*)s_W1)[tid + i*256] = *(const float4*)(sfc1w + f*4096 + (tid + i*256)*4);
        ((float4*)s_Wsk)[tid] = *(const float4*)(sskw + f*1024 + tid*4);
        __syncthreads();
        #pragma unroll 8
        for (int k = 0; k < 64; k++){
            float xv = s_xp[m*65 + k];
            const float4* wr = (const float4*)(s_W1 + k*64 + j0);
            float4 w0 = wr[0], w1 = wr[1];
            accS[0] += xv*w0.x; accS[1] += xv*w0.y; accS[2] += xv*w0.z; accS[3] += xv*w0.w;
            accS[4] += xv*w1.x; accS[5] += xv*w1.y; accS[6] += xv*w1.z; accS[7] += xv*w1.w;
            float2 wk = *(const float2*)(s_Wsk + k*16 + g8*2);
            accK0 += xv*wk.x; accK1 += xv*wk.y;
        }
        __syncthreads();
    }

    #pragma unroll
    for (int i = 0; i < 8; i++)
        s_h[m*65 + j0 + i] = eluf(accS[i] + sfc1b[j0+i]);
    ((float4*)s_W1)[tid]       = *(const float4*)(sfc2w + tid*4);
    ((float4*)s_W1)[tid + 256] = *(const float4*)(sfc2w + 1024 + tid*4);
    __syncthreads();

    {
        const int jj = g8 * 4;
        float a0 = 0.f, a1 = 0.f, a2 = 0.f, a3 = 0.f;
        #pragma unroll 8
        for (int k = 0; k < 64; k++){
            float hv = s_h[m*65 + k];
            float4 w = *(const float4*)(s_W1 + k*32 + jj);
            a0 += hv*w.x; a1 += hv*w.y; a2 += hv*w.z; a3 += hv*w.w;
        }
        s_sel2[m*32 + jj+0] = a0 + sfc2b[jj+0];
        s_sel2[m*32 + jj+1] = a1 + sfc2b[jj+1];
        s_sel2[m*32 + jj+2] = a2 + sfc2b[jj+2];
        s_sel2[m*32 + jj+3] = a3 + sfc2b[jj+3];
    }
    __syncthreads();

    {
        const int f0 = g8 * 2;
        float a0 = s_sel2[m*32 + f0],   g0 = s_sel2[m*32 + 16 + f0];
        float a1 = s_sel2[m*32 + f0+1], g1 = s_sel2[m*32 + 16 + f0+1];
        float pre0 = a0*sigf(g0) + accK0 + sskb[f0];
        float pre1 = a1*sigf(g1) + accK1 + sskb[f0+1];
        float sum = pre0 + pre1;
        sum += __shfl_xor(sum,1,8); sum += __shfl_xor(sum,2,8); sum += __shfl_xor(sum,4,8);
        float mean = sum * 0.0625f;
        float d0 = pre0 - mean, d1 = pre1 - mean;
        float vv = d0*d0 + d1*d1;
        vv += __shfl_xor(vv,1,8); vv += __shfl_xor(vv,2,8); vv += __shfl_xor(vv,4,8);
        float rstd = rsqrtf(vv * 0.0625f + 1e-5f);
        float sv0 = d0*rstd*slng[f0]   + slnb[f0];
        float sv1 = d1*rstd*slng[f0+1] + slnb[f0+1];
        float mx = fmaxf(sv0, sv1);
        mx = fmaxf(mx, __shfl_xor(mx,1,8));
        mx = fmaxf(mx, __shfl_xor(mx,2,8));
        mx = fmaxf(mx, __shfl_xor(mx,4,8));
        float e0 = __expf(sv0 - mx), e1 = __expf(sv1 - mx);
        float es = e0 + e1;
        es += __shfl_xor(es,1,8); es += __shfl_xor(es,2,8); es += __shfl_xor(es,4,8);
        float inv = 1.f / es;
        s_wsm[m*16 + f0]   = e0 * inv;
        s_wsm[m*16 + f0+1] = e1 * inv;
    }
    __syncthreads();

    float accV[8];
    #pragma unroll
    for (int i = 0; i < 8; i++) accV[i] = 0.f;

    for (int f = 0; f < 16; f++){
        {
            float xb = s_x[m*16 + f];
            #pragma unroll
            for (int i = 0; i < 8; i++)
                s_xp[m*65 + j0 + i] = xb * s_ipw[j0+i] + s_ipb[j0+i];
        }
        #pragma unroll
        for (int i = 0; i < 4; i++)
            ((float4*)s_W1)[tid + i*256] = *(const float4*)(vfc1w + f*4096 + (tid + i*256)*4);
        #pragma unroll
        for (int i = 0; i < 8; i++)
            ((float4*)s_W2)[tid + i*256] = *(const float4*)(vfc2w + f*8192 + (tid + i*256)*4);
        if (tid < 16)       ((float4*)s_b1)[tid]     = *(const float4*)(vfc1b + f*64  + tid*4);
        else if (tid < 48)  ((float4*)s_b2)[tid-16]  = *(const float4*)(vfc2b + f*128 + (tid-16)*4);
        else if (tid < 64)  ((float4*)s_lng)[tid-48] = *(const float4*)(vlng  + f*64  + (tid-48)*4);
        else if (tid < 80)  ((float4*)s_lnb)[tid-64] = *(const float4*)(vlnb  + f*64  + (tid-64)*4);
        __syncthreads();

        float ah[8];
        #pragma unroll
        for (int i = 0; i < 8; i++) ah[i] = 0.f;
        #pragma unroll 8
        for (int k = 0; k < 64; k++){
            float xv = s_xp[m*65 + k];
            const float4* wr = (const float4*)(s_W1 + k*64 + j0);
            float4 w0 = wr[0], w1 = wr[1];
            ah[0] += xv*w0.x; ah[1] += xv*w0.y; ah[2] += xv*w0.z; ah[3] += xv*w0.w;
            ah[4] += xv*w1.x; ah[5] += xv*w1.y; ah[6] += xv*w1.z; ah[7] += xv*w1.w;
        }
        #pragma unroll
        for (int i = 0; i < 8; i++)
            s_h[m*65 + j0 + i] = eluf(ah[i] + s_b1[j0+i]);
        __syncthreads();

        float aa[8], ag[8];
        #pragma unroll
        for (int i = 0; i < 8; i++){ aa[i] = 0.f; ag[i] = 0.f; }
        #pragma unroll 4
        for (int k = 0; k < 64; k++){
            float hv = s_h[m*65 + k];
            const float4* war = (const float4*)(s_W2 + k*128 + j0);
            const float4* wgr = (const float4*)(s_W2 + k*128 + 64 + j0);
            float4 wa0 = war[0], wa1 = war[1];
            float4 wg0 = wgr[0], wg1 = wgr[1];
            aa[0] += hv*wa0.x; aa[1] += hv*wa0.y; aa[2] += hv*wa0.z; aa[3] += hv*wa0.w;
            aa[4] += hv*wa1.x; aa[5] += hv*wa1.y; aa[6] += hv*wa1.z; aa[7] += hv*wa1.w;
            ag[0] += hv*wg0.x; ag[1] += hv*wg0.y; ag[2] += hv*wg0.z; ag[3] += hv*wg0.w;
            ag[4] += hv*wg1.x; ag[5] += hv*wg1.y; ag[6] += hv*wg1.z; ag[7] += hv*wg1.w;
        }
        float pre[8];
        float lsum = 0.f;
        #pragma unroll
        for (int i = 0; i < 8; i++){
            float av = aa[i] + s_b2[j0+i];
            float gv = ag[i] + s_b2[64 + j0+i];
            pre[i] = av * sigf(gv) + s_xp[m*65 + j0 + i];
            lsum += pre[i];
        }
        lsum += __shfl_xor(lsum,1,8); lsum += __shfl_xor(lsum,2,8); lsum += __shfl_xor(lsum,4,8);
        float mean = lsum * 0.015625f;
        float lvar = 0.f;
        #pragma unroll
        for (int i = 0; i < 8; i++){ float d = pre[i] - mean; lvar += d*d; }
        lvar += __shfl_xor(lvar,1,8); lvar += __shfl_xor(lvar,2,8); lvar += __shfl_xor(lvar,4,8);
        float rstd = rsqrtf(lvar * 0.015625f + 1e-5f);
        float wf = s_wsm[m*16 + f];
        #pragma unroll
        for (int i = 0; i < 8; i++)
            accV[i] += wf * ((pre[i] - mean) * rstd * s_lng[j0+i] + s_lnb[j0+i]);
        __syncthreads();
    }

    float4 o0 = make_float4(accV[0], accV[1], accV[2], accV[3]);
    float4 o1 = make_float4(accV[4], accV[5], accV[6], accV[7]);
    *(float4*)(vsn_out + (pos0 + m)*64 + j0)     = o0;
    *(float4*)(vsn_out + (pos0 + m)*64 + j0 + 4) = o1;
}

// ---------------------------------------------------------------------------
// Kernel 2: gpre = vsn_out @ w_ih[0] + b[0]   (unchanged)
// ---------------------------------------------------------------------------
__global__ __launch_bounds__(256) void tft_xgates_kernel(
    const float* __restrict__ vsn, const float* __restrict__ w_ih,
    const float* __restrict__ bias, float* __restrict__ gpre)
{
    __shared__ __align__(16) float s_w[64*256];
    __shared__ __align__(16) float s_vT[64*20];
    __shared__ __align__(16) float s_b[256];
    const int tid  = threadIdx.x;
    const int pos0 = blockIdx.x * 16;

    #pragma unroll
    for (int i = 0; i < 16; i++)
        ((float4*)s_w)[tid + i*256] = *(const float4*)(w_ih + (tid + i*256)*4);
    s_b[tid] = bias[tid];
    {
        int mm = tid >> 4;
        int k0 = (tid & 15) * 4;
        float4 v = *(const float4*)(vsn + (pos0 + mm)*64 + k0);
        s_vT[(k0+0)*20 + mm] = v.x;
        s_vT[(k0+1)*20 + mm] = v.y;
        s_vT[(k0+2)*20 + mm] = v.z;
        s_vT[(k0+3)*20 + mm] = v.w;
    }
    __syncthreads();

    float acc[16];
    #pragma unroll
    for (int i = 0; i < 16; i++) acc[i] = 0.f;
    #pragma unroll 8
    for (int k = 0; k < 64; k++){
        float wv = s_w[k*256 + tid];
        const float4* vr = (const float4*)(s_vT + k*20);
        float4 v0 = vr[0], v1 = vr[1], v2 = vr[2], v3 = vr[3];
        acc[0]  += wv*v0.x; acc[1]  += wv*v0.y; acc[2]  += wv*v0.z; acc[3]  += wv*v0.w;
        acc[4]  += wv*v1.x; acc[5]  += wv*v1.y; acc[6]  += wv*v1.z; acc[7]  += wv*v1.w;
        acc[8]  += wv*v2.x; acc[9]  += wv*v2.y; acc[10] += wv*v2.z; acc[11] += wv*v2.w;
        acc[12] += wv*v3.x; acc[13] += wv*v3.y; acc[14] += wv*v3.z; acc[15] += wv*v3.w;
    }
    float bv = s_b[tid];
    #pragma unroll
    for (int i = 0; i < 16; i++)
        gpre[(pos0 + i)*256 + tid] = acc[i] + bv;
}

// ---------------------------------------------------------------------------
// Kernel 3: 2-layer LSTM — round-11: WEIGHTS IN LDS.
// r3-r10 lesson: the compiler will not keep >~100 weight floats/thread in
// arch VGPRs (sinks loads into the loop -> ~2000cy/step of L2 traffic, or
// AGPR-shuffles them).  Fix: stage whh1 + whh2 (128 KB) in LDS ONCE; read
// per-step from LDS (conflict-free: consecutive lanes -> consecutive addrs;
// 128 KB/step at ~256 B/cy ~= 512 cy, overlapped with FMA issue).  wih2
// stays in registers (only 8 float4/thread with the K-split -> ~75 VGPR
// need, inside the allocator's comfort zone).  Otherwise exact r4 skeleton:
// 512 thr, 1 block/batch, K-split by 2, lagged L2, 2 lgkm-only barriers/
// step, 2-deep gpre register FIFO.
// ---------------------------------------------------------------------------
#define LDW4(P, i) make_float4((P)[(4*(i)+0)*256], (P)[(4*(i)+1)*256], \
                               (P)[(4*(i)+2)*256], (P)[(4*(i)+3)*256])

#define LSTM_CH(c) {                                                        \
    float4 h1c = h1b[c];                                                    \
    a10 += h1c.x * s_w1[wbase + (4*(c)+0)*256];                             \
    a11 += h1c.y * s_w1[wbase + (4*(c)+1)*256];                             \
    a12 += h1c.z * s_w1[wbase + (4*(c)+2)*256];                             \
    a13 += h1c.w * s_w1[wbase + (4*(c)+3)*256];                             \
    a20 += h1c.x * WX_##c.x; a21 += h1c.y * WX_##c.y;                       \
    a22 += h1c.z * WX_##c.z; a23 += h1c.w * WX_##c.w;                       \
    float4 h2c = h2b[c];                                                    \
    a20 += h2c.x * s_wh[wbase + (4*(c)+0)*256];                             \
    a21 += h2c.y * s_wh[wbase + (4*(c)+1)*256];                             \
    a22 += h2c.z * s_wh[wbase + (4*(c)+2)*256];                             \
    a23 += h2c.w * s_wh[wbase + (4*(c)+3)*256];                             \
}

__global__ __launch_bounds__(512, 1) void tft_lstm_kernel(
    const float* __restrict__ w_ih, const float* __restrict__ w_hh,
    const float* __restrict__ bias, const float* __restrict__ gpre,
    float* __restrict__ seq)
{
    __shared__ __align__(16) float s_w1[64*256];   // whh1 row-major [k][gate]
    __shared__ __align__(16) float s_wh[64*256];   // whh2 row-major [k][gate]
    __shared__ __align__(16) float s_h1[64];
    __shared__ __align__(16) float s_h2[64];
    __shared__ __align__(16) float s_g1h[512];     // [half][gate]
    __shared__ __align__(16) float s_g2h[512];
    __shared__ __align__(16) float s_gp[256];

    const int tid  = threadIdx.x;
    const int b    = blockIdx.x;
    const int g    = tid & 255;
    const int half = tid >> 8;       // wave-uniform (waves 0-3 vs 4-7)
    const int koff = half * 32;
    const int wbase = koff * 256 + g;    // LDS float index of (row koff, col g)

    // ---- stage whh1 and whh2 into LDS once (coalesced float4) ----
    #pragma unroll
    for (int i = 0; i < 8; i++)
        ((float4*)s_w1)[tid + i*512] = ((const float4*)w_hh)[tid + i*512];
    #pragma unroll
    for (int i = 0; i < 8; i++)
        ((float4*)s_wh)[tid + i*512] = ((const float4*)(w_hh + 16384))[tid + i*512];

    // ---- wih2 column g, rows [koff, koff+32): 8 named float4 registers ----
    const float* px = w_ih + 16384 + koff*256 + g;
    float4 WX_0 = LDW4(px,0), WX_1 = LDW4(px,1), WX_2 = LDW4(px,2), WX_3 = LDW4(px,3);
    float4 WX_4 = LDW4(px,4), WX_5 = LDW4(px,5), WX_6 = LDW4(px,6), WX_7 = LDW4(px,7);

    const float b2 = (half == 0) ? bias[256 + g] : 0.f;   // L2 bias added once

    if (tid < 64) s_h1[tid] = 0.f;
    else if (tid < 128) s_h2[tid - 64] = 0.f;

    const float* gpb = gpre + (size_t)b * 512 * 256 + g;
    float gp_w = 0.f, gp_l = 0.f;
    if (half == 0){
        s_gp[g] = gpb[0];       // x-gates for t=0 (bias included)
        gp_w    = gpb[256];     // t=1 (published at ACT(0))
        gp_l    = gpb[512];     // t=2 (published at ACT(1))
    }
    float c1 = 0.f, c2 = 0.f;   // live in wave0 / wave1 lanes
    __syncthreads();

    const float4* h1b = (const float4*)s_h1 + half*8;
    const float4* h2b = (const float4*)s_h2 + half*8;
    float* seqb = seq + (size_t)b * 512 * 64;

    for (int n = 0; n <= 512; ++n){
        // ---- GATE phase: all 512 threads, half-dots ----
        float a10 = (half == 0) ? s_gp[g] : 0.f;
        float a11 = 0.f, a12 = 0.f, a13 = 0.f;            // L1 gate g, t=n
        float a20 = b2, a21 = 0.f, a22 = 0.f, a23 = 0.f;  // L2 gate g, t=n-1
        LSTM_CH(0) LSTM_CH(1) LSTM_CH(2) LSTM_CH(3)
        LSTM_CH(4) LSTM_CH(5) LSTM_CH(6) LSTM_CH(7)
        float gp_n = 0.f;
        if (half == 0 && n + 3 < 512) gp_n = gpb[(n + 3) * 256];  // 2-deep FIFO
        s_g1h[half*256 + g] = (a10 + a11) + (a12 + a13);
        s_g2h[half*256 + g] = (a20 + a21) + (a22 + a23);
        BARRIER_LGKM();

        // ---- ACT phase: wave0 -> L1 state; wave1 -> L2 state + seq store ----
        if (tid < 64 && n < 512){
            float gi = s_g1h[tid]     + s_g1h[256+tid];
            float gf = s_g1h[64+tid]  + s_g1h[320+tid];
            float gg = s_g1h[128+tid] + s_g1h[384+tid];
            float go = s_g1h[192+tid] + s_g1h[448+tid];
            c1 = sigf(gf)*c1 + sigf(gi)*tanhf_(gg);
            s_h1[tid] = sigf(go)*tanhf_(c1);
        } else if (tid >= 64 && tid < 128 && n >= 1){
            int j = tid - 64;
            float gi = s_g2h[j]     + s_g2h[256+j];
            float gf = s_g2h[64+j]  + s_g2h[320+j];
            float gg = s_g2h[128+j] + s_g2h[384+j];
            float go = s_g2h[192+j] + s_g2h[448+j];
            c2 = sigf(gf)*c2 + sigf(gi)*tanhf_(gg);
            float h2v = sigf(go)*tanhf_(c2);
            s_h2[j] = h2v;
            seqb[(size_t)(n - 1)*64 + j] = h2v;   // store ack never drained
        }
        if (half == 0 && n + 1 < 512) s_gp[g] = gp_w;  // publish t=n+1 x-gates
        gp_w = gp_l; gp_l = gp_n;
        BARRIER_LGKM();
    }
}

// ---------------------------------------------------------------------------
// Kernel 4: lo = LN(GLU(seq) + vsn_out); K,V; q/lo at t=T-1.  (unchanged)
// ---------------------------------------------------------------------------
__global__ __launch_bounds__(256) void tft_lokv_kernel(
    const float* __restrict__ seq, const float* __restrict__ vsn,
    const float* __restrict__ plgw, const float* __restrict__ plgb,
    const float* __restrict__ png,  const float* __restrict__ pnb,
    const float* __restrict__ qkvw, const float* __restrict__ qkvb,
    float* __restrict__ kbuf, float* __restrict__ vbuf,
    float* __restrict__ qlast, float* __restrict__ lolast)
{
    __shared__ __align__(16) float s_pw[64*128];
    __shared__ __align__(16) float s_qw[64*192];
    __shared__ __align__(16) float s_pb[128];
    __shared__ __align__(16) float s_png[64];
    __shared__ __align__(16) float s_pnb[64];
    __shared__ __align__(16) float s_qb[192];
    __shared__ __align__(16) float s_row[4][64];
    __shared__ __align__(16) float s_lo[4][64];

    const int tid  = threadIdx.x;
    const int lane = tid & 63;
    const int wid  = tid >> 6;

    #pragma unroll
    for (int i = 0; i < 8; i++)
        ((float4*)s_pw)[tid + i*256] = *(const float4*)(plgw + (tid + i*256)*4);
    #pragma unroll
    for (int i = 0; i < 12; i++)
        ((float4*)s_qw)[tid + i*256] = *(const float4*)(qkvw + (tid + i*256)*4);
    if (tid < 128) s_pb[tid] = plgb[tid];
    if (tid < 64){ s_png[tid] = png[tid]; s_pnb[tid] = pnb[tid]; }
    if (tid < 192) s_qb[tid] = qkvb[tid];
    __syncthreads();

    for (int it = 0; it < 16; it++){
        int mpos = blockIdx.x*64 + wid*16 + it;
        int b = mpos >> 9, t = mpos & 511;
        float sv = seq[mpos*64 + lane];
        float vs = vsn[mpos*64 + lane];
        s_row[wid][lane] = sv;
        __syncthreads();
        float a = s_pb[lane], g = s_pb[64 + lane];
        #pragma unroll 8
        for (int k = 0; k < 64; k++){
            float rv = s_row[wid][k];
            a += rv * s_pw[k*128 + lane];
            g += rv * s_pw[k*128 + 64 + lane];
        }
        float pre = a * sigf(g) + vs;
        float mean = wsum64(pre) * 0.015625f;
        float d = pre - mean;
        float vv = wsum64(d*d) * 0.015625f;
        float lo = d * rsqrtf(vv + 1e-5f) * s_png[lane] + s_pnb[lane];
        s_lo[wid][lane] = lo;
        __syncthreads();
        float ka = s_qb[64 + lane], va = s_qb[128 + lane];
        #pragma unroll 8
        for (int k = 0; k < 64; k++){
            float lv = s_lo[wid][k];
            ka += lv * s_qw[k*192 + 64 + lane];
            va += lv * s_qw[k*192 + 128 + lane];
        }
        int h = lane >> 4, dd = lane & 15;
        kbuf[((b*4 + h)*512 + t)*16 + dd] = ka;
        vbuf[((b*4 + h)*512 + t)*16 + dd] = va;
        if (t == 511){
            float qa = s_qb[lane];
            #pragma unroll 8
            for (int k = 0; k < 64; k++)
                qa += s_lo[wid][k] * s_qw[k*192 + lane];
            qlast[b*64 + lane] = qa;
            lolast[b*64 + lane] = lo;
        }
    }
}

// ---------------------------------------------------------------------------
// Kernel 5: head (attention at t=T-1 + GRNs + out).  (unchanged)
// ---------------------------------------------------------------------------
__global__ __launch_bounds__(256) void tft_head_kernel(
    const float* __restrict__ kbuf, const float* __restrict__ vbuf,
    const float* __restrict__ qlast, const float* __restrict__ lolast,
    const float* __restrict__ aow,  const float* __restrict__ aob,
    const float* __restrict__ pagw, const float* __restrict__ pagb,
    const float* __restrict__ pang, const float* __restrict__ panb,
    const float* __restrict__ ff1w, const float* __restrict__ ff1b,
    const float* __restrict__ ff2w, const float* __restrict__ ff2b,
    const float* __restrict__ fflng, const float* __restrict__ fflnb,
    const float* __restrict__ fng,  const float* __restrict__ fnb,
    const float* __restrict__ outw, const float* __restrict__ outb,
    float* __restrict__ out)
{
    __shared__ __align__(16) float s_q[64];
    __shared__ __align__(16) float s_lo[64];
    __shared__ __align__(16) float s_sc[4*512];
    __shared__ __align__(16) float s_part[4][64];
    __shared__ __align__(16) float s_a[64];
    __shared__ __align__(16) float s_a2[64];
    __shared__ __align__(16) float s_z[128];
    __shared__ __align__(16) float s_at[64];
    __shared__ __align__(16) float s_f1[256];

    const int tid = threadIdx.x;
    const int b   = blockIdx.x;
    if (tid < 64){ s_q[tid] = qlast[b*64 + tid]; s_lo[tid] = lolast[b*64 + tid]; }
    __syncthreads();

    for (int idx = tid; idx < 2048; idx += 256){
        int h = idx >> 9, t = idx & 511;
        const float4* kr = (const float4*)(kbuf + ((b*4 + h)*512 + t)*16);
        const float4* qr = (const float4*)(s_q + h*16);
        float4 k0 = kr[0], k1 = kr[1], k2 = kr[2], k3 = kr[3];
        float4 q0 = qr[0], q1 = qr[1], q2 = qr[2], q3 = qr[3];
        float d = q0.x*k0.x + q0.y*k0.y + q0.z*k0.z + q0.w*k0.w
                + q1.x*k1.x + q1.y*k1.y + q1.z*k1.z + q1.w*k1.w
                + q2.x*k2.x + q2.y*k2.y + q2.z*k2.z + q2.w*k2.w
                + q3.x*k3.x + q3.y*k3.y + q3.z*k3.z + q3.w*k3.w;
        s_sc[idx] = d * 0.25f;
    }
    __syncthreads();
    {
        int h = tid >> 6, lane = tid & 63;
        float v[8];
        float mx = -1e30f;
        #pragma unroll
        for (int j = 0; j < 8; j++){ v[j] = s_sc[h*512 + lane + j*64]; mx = fmaxf(mx, v[j]); }
        mx = wmax64(mx);
        float sum = 0.f;
        #pragma unroll
        for (int j = 0; j < 8; j++){ v[j] = __expf(v[j] - mx); sum += v[j]; }
        sum = wsum64(sum);
        float inv = 1.f / sum;
        #pragma unroll
        for (int j = 0; j < 8; j++) s_sc[h*512 + lane + j*64] = v[j] * inv;
    }
    __syncthreads();
    {
        int j = tid & 63, part = tid >> 6;
        int h = j >> 4, dd = j & 15;
        float pa = 0.f;
        for (int t = part*128; t < (part+1)*128; t++)
            pa += s_sc[h*512 + t] * vbuf[((b*4 + h)*512 + t)*16 + dd];
        s_part[part][j] = pa;
    }
    __syncthreads();
    if (tid < 64) s_a[tid] = s_part[0][tid] + s_part[1][tid] + s_part[2][tid] + s_part[3][tid];
    __syncthreads();
    if (tid < 64){
        float o = aob[tid];
        #pragma unroll 8
        for (int k = 0; k < 64; k++) o += s_a[k] * aow[k*64 + tid];
        s_a2[tid] = o;
    }
    __syncthreads();
    if (tid < 128){
        float z = pagb[tid];
        #pragma unroll 8
        for (int k = 0; k < 64; k++) z += s_a2[k] * pagw[k*128 + tid];
        s_z[tid] = z;
    }
    __syncthreads();
    if (tid < 64){
        float pre = s_z[tid] * sigf(s_z[64 + tid]) + s_lo[tid];
        float mean = wsum64(pre) * 0.015625f;
        float d = pre - mean;
        float vv = wsum64(d*d) * 0.015625f;
        s_at[tid] = d * rsqrtf(vv + 1e-5f) * pang[tid] + panb[tid];
    }
    __syncthreads();
    {
        float hv = ff1b[tid];
        #pragma unroll 8
        for (int k = 0; k < 64; k++) hv += s_at[k] * ff1w[k*256 + tid];
        s_f1[tid] = eluf(hv);
    }
    __syncthreads();
    if (tid < 128){
        float z = ff2b[tid];
        #pragma unroll 8
        for (int k = 0; k < 256; k++) z += s_f1[k] * ff2w[k*128 + tid];
        s_z[tid] = z;
    }
    __syncthreads();
    if (tid < 64){
        float pre = s_z[tid] * sigf(s_z[64 + tid]) + s_at[tid];
        float mean = wsum64(pre) * 0.015625f;
        float d = pre - mean;
        float vv = wsum64(d*d) * 0.015625f;
        float ffv = d * rsqrtf(vv + 1e-5f) * fflng[tid] + fflnb[tid];
        float pre2 = ffv + s_at[tid];
        float mean2 = wsum64(pre2) * 0.015625f;
        float d2 = pre2 - mean2;
        float v2 = wsum64(d2*d2) * 0.015625f;
        float f2 = d2 * rsqrtf(v2 + 1e-5f) * fng[tid] + fnb[tid];
        float p = wsum64(f2 * outw[tid]);
        if (tid == 0) out[b] = p + outb[0];
    }
}

// ---------------------------------------------------------------------------
extern "C" void kernel_launch(void* const* d_in, const int* in_sizes, int n_in,
                              void* d_out, int out_size, void* d_ws, size_t ws_size,
                              hipStream_t stream)
{
    const float* x     = (const float*)d_in[0];
    const float* ip_w  = (const float*)d_in[1];
    const float* ip_b  = (const float*)d_in[2];
    const float* vfc1w = (const float*)d_in[3];
    const float* vfc1b = (const float*)d_in[4];
    const float* vfc2w = (const float*)d_in[5];
    const float* vfc2b = (const float*)d_in[6];
    const float* vlng  = (const float*)d_in[7];
    const float* vlnb  = (const float*)d_in[8];
    const float* sfc1w = (const float*)d_in[9];
    const float* sfc1b = (const float*)d_in[10];
    const float* sfc2w = (const float*)d_in[11];
    const float* sfc2b = (const float*)d_in[12];
    const float* sskw  = (const float*)d_in[13];
    const float* sskb  = (const float*)d_in[14];
    const float* slng  = (const float*)d_in[15];
    const float* slnb  = (const float*)d_in[16];
    const float* lwih  = (const float*)d_in[17];
    const float* lwhh  = (const float*)d_in[18];
    const float* lb    = (const float*)d_in[19];
    const float* plgw  = (const float*)d_in[20];
    const float* plgb  = (const float*)d_in[21];
    const float* plng  = (const float*)d_in[22];
    const float* plnb  = (const float*)d_in[23];
    const float* qkvw  = (const float*)d_in[24];
    const float* qkvb  = (const float*)d_in[25];
    const float* aow   = (const float*)d_in[26];
    const float* aob   = (const float*)d_in[27];
    const float* pagw  = (const float*)d_in[28];
    const float* pagb  = (const float*)d_in[29];
    const float* pang  = (const float*)d_in[30];
    const float* panb  = (const float*)d_in[31];
    const float* ff1w  = (const float*)d_in[32];
    const float* ff1b  = (const float*)d_in[33];
    const float* ff2w  = (const float*)d_in[34];
    const float* ff2b  = (const float*)d_in[35];
    const float* fflng = (const float*)d_in[36];
    const float* fflnb = (const float*)d_in[37];
    const float* fng   = (const float*)d_in[38];
    const float* fnb   = (const float*)d_in[39];
    const float* outw  = (const float*)d_in[40];
    const float* outb  = (const float*)d_in[41];

    float* ws      = (float*)d_ws;
    float* vsn_out = ws;                    // 16384*64    = 1,048,576 f
    float* seq     = ws + 1048576;          // 16384*64    = 1,048,576 f
    float* gpre    = ws + 2*1048576;        // 16384*256   = 4,194,304 f
    float* kbuf    = ws + 6*1048576;        // 32*4*512*16 = 1,048,576 f
    float* vbuf    = ws + 7*1048576;        // 1,048,576 f
    float* qlast   = ws + 8*1048576;        // 2048 f
    float* lolast  = qlast + 2048;          // 2048 f
    float* outp    = (float*)d_out;

    tft_vsn_kernel<<<512, 256, 0, stream>>>(x, ip_w, ip_b, vfc1w, vfc1b, vfc2w, vfc2b,
                                            vlng, vlnb, sfc1w, sfc1b, sfc2w, sfc2b,
                                            sskw, sskb, slng, slnb, vsn_out);
    tft_xgates_kernel<<<1024, 256, 0, stream>>>(vsn_out, lwih, lb, gpre);
    tft_lstm_kernel<<<32, 512, 0, stream>>>(lwih, lwhh, lb, gpre, seq);
    tft_lokv_kernel<<<256, 256, 0, stream>>>(seq, vsn_out, plgw, plgb, plng, plnb,
                                             qkvw, qkvb, kbuf, vbuf, qlast, lolast);
    tft_head_kernel<<<32, 256, 0, stream>>>(kbuf, vbuf, qlast, lolast, aow, aob,
                                            pagw, pagb, pang, panb, ff1w, ff1b,
                                            ff2w, ff2b, fflng, fflnb, fng, fnb,
                                            outw, outb, outp);
}

// Round 12
// 765.425 us; speedup vs baseline: 1.3052x; 1.3052x over previous
//
#include <hip/hip_runtime.h>
#include <math.h>

// Problem dims: B=32, T=512, F=16, H=64, NH=4, HD=16, L=2.  BT=16384.

__device__ __forceinline__ float sigf(float x){
    return 1.f / (1.f + __expf(-x));
}
__device__ __forceinline__ float tanhf_(float x){
    float xc = fminf(fmaxf(x, -15.f), 15.f);   // clamp: avoid inf/inf NaN
    float e = __expf(-2.f * xc);
    return (1.f - e) / (1.f + e);
}
__device__ __forceinline__ float eluf(float x){
    return x > 0.f ? x : (__expf(x) - 1.f);
}
__device__ __forceinline__ float wsum64(float v){
    #pragma unroll
    for (int o = 1; o < 64; o <<= 1) v += __shfl_xor(v, o, 64);
    return v;
}
__device__ __forceinline__ float wmax64(float v){
    #pragma unroll
    for (int o = 1; o < 64; o <<= 1) v = fmaxf(v, __shfl_xor(v, o, 64));
    return v;
}

// Barrier that waits only for LDS ops (NOT vmcnt) — global stores/loads stay
// in flight across it (__syncthreads would drain vmcnt(0)).
#define BARRIER_LGKM() do {                                    \
    asm volatile("s_waitcnt lgkmcnt(0)" ::: "memory");         \
    __builtin_amdgcn_s_barrier();                              \
} while(0)

// ---------------------------------------------------------------------------
// Kernel 1: VSN v2 — 64 positions/block, 512 threads, 256 blocks.
// Round-12 change: doubling the position tile halves the per-feature weight
// restage traffic (the VSN bottleneck: ~565 MB of L2 reads at 32-pos tiles).
// Thread -> (m = tid>>3 in [0,64), g8 = tid&7, j0 = g8*8): 8 cols per thread.
// ---------------------------------------------------------------------------
__global__ __launch_bounds__(512) void tft_vsn_kernel(
    const float* __restrict__ x,
    const float* __restrict__ ip_w, const float* __restrict__ ip_b,
    const float* __restrict__ vfc1w, const float* __restrict__ vfc1b,
    const float* __restrict__ vfc2w, const float* __restrict__ vfc2b,
    const float* __restrict__ vlng, const float* __restrict__ vlnb,
    const float* __restrict__ sfc1w, const float* __restrict__ sfc1b,
    const float* __restrict__ sfc2w, const float* __restrict__ sfc2b,
    const float* __restrict__ sskw, const float* __restrict__ sskb,
    const float* __restrict__ slng, const float* __restrict__ slnb,
    float* __restrict__ vsn_out)
{
    __shared__ __align__(16) float s_x[64*16];      // 4 KB
    __shared__ __align__(16) float s_ipw[64];
    __shared__ __align__(16) float s_ipb[64];
    __shared__ __align__(16) float s_xp[64*65];     // 16.6 KB (padded)
    __shared__ __align__(16) float s_W1[64*64];     // 16 KB
    __shared__ __align__(16) float s_W2[64*128];    // 32 KB
    __shared__ __align__(16) float s_Wsk[64*16];    // 4 KB
    __shared__ __align__(16) float s_h[64*65];      // 16.6 KB
    __shared__ __align__(16) float s_sel2[64*32];   // 8 KB
    __shared__ __align__(16) float s_wsm[64*16];    // 4 KB
    __shared__ __align__(16) float s_lng[64];
    __shared__ __align__(16) float s_lnb[64];
    __shared__ __align__(16) float s_b1[64];
    __shared__ __align__(16) float s_b2[128];

    const int tid  = threadIdx.x;
    const int pos0 = blockIdx.x * 64;
    const int m    = tid >> 3;
    const int g8   = tid & 7;
    const int j0   = g8 * 8;

    if (tid < 256) ((float4*)s_x)[tid] = *(const float4*)(x + pos0*16 + tid*4);
    if (tid < 64) { s_ipw[tid] = ip_w[tid]; s_ipb[tid] = ip_b[tid]; }
    __syncthreads();

    float accS[8];
    #pragma unroll
    for (int i = 0; i < 8; i++) accS[i] = 0.f;
    float accK0 = 0.f, accK1 = 0.f;

    // ---------------- pass 1: selection-weight path ----------------
    for (int f = 0; f < 16; f++){
        {
            float xb = s_x[m*16 + f];
            #pragma unroll
            for (int i = 0; i < 8; i++)
                s_xp[m*65 + j0 + i] = xb * s_ipw[j0+i] + s_ipb[j0+i];
        }
        #pragma unroll
        for (int i = 0; i < 2; i++)
            ((float4*)s_W1)[tid + i*512] = *(const float4*)(sfc1w + f*4096 + (tid + i*512)*4);
        if (tid < 256) ((float4*)s_Wsk)[tid] = *(const float4*)(sskw + f*1024 + tid*4);
        __syncthreads();
        #pragma unroll 8
        for (int k = 0; k < 64; k++){
            float xv = s_xp[m*65 + k];
            const float4* wr = (const float4*)(s_W1 + k*64 + j0);
            float4 w0 = wr[0], w1 = wr[1];
            accS[0] += xv*w0.x; accS[1] += xv*w0.y; accS[2] += xv*w0.z; accS[3] += xv*w0.w;
            accS[4] += xv*w1.x; accS[5] += xv*w1.y; accS[6] += xv*w1.z; accS[7] += xv*w1.w;
            float2 wk = *(const float2*)(s_Wsk + k*16 + g8*2);
            accK0 += xv*wk.x; accK1 += xv*wk.y;
        }
        __syncthreads();
    }

    #pragma unroll
    for (int i = 0; i < 8; i++)
        s_h[m*65 + j0 + i] = eluf(accS[i] + sfc1b[j0+i]);
    ((float4*)s_W1)[tid] = *(const float4*)(sfc2w + tid*4);   // 2048 f = 512 f4
    __syncthreads();

    {
        const int jj = g8 * 4;
        float a0 = 0.f, a1 = 0.f, a2 = 0.f, a3 = 0.f;
        #pragma unroll 8
        for (int k = 0; k < 64; k++){
            float hv = s_h[m*65 + k];
            float4 w = *(const float4*)(s_W1 + k*32 + jj);
            a0 += hv*w.x; a1 += hv*w.y; a2 += hv*w.z; a3 += hv*w.w;
        }
        s_sel2[m*32 + jj+0] = a0 + sfc2b[jj+0];
        s_sel2[m*32 + jj+1] = a1 + sfc2b[jj+1];
        s_sel2[m*32 + jj+2] = a2 + sfc2b[jj+2];
        s_sel2[m*32 + jj+3] = a3 + sfc2b[jj+3];
    }
    __syncthreads();

    {
        const int f0 = g8 * 2;
        float a0 = s_sel2[m*32 + f0],   g0 = s_sel2[m*32 + 16 + f0];
        float a1 = s_sel2[m*32 + f0+1], g1 = s_sel2[m*32 + 16 + f0+1];
        float pre0 = a0*sigf(g0) + accK0 + sskb[f0];
        float pre1 = a1*sigf(g1) + accK1 + sskb[f0+1];
        float sum = pre0 + pre1;
        sum += __shfl_xor(sum,1,8); sum += __shfl_xor(sum,2,8); sum += __shfl_xor(sum,4,8);
        float mean = sum * 0.0625f;
        float d0 = pre0 - mean, d1 = pre1 - mean;
        float vv = d0*d0 + d1*d1;
        vv += __shfl_xor(vv,1,8); vv += __shfl_xor(vv,2,8); vv += __shfl_xor(vv,4,8);
        float rstd = rsqrtf(vv * 0.0625f + 1e-5f);
        float sv0 = d0*rstd*slng[f0]   + slnb[f0];
        float sv1 = d1*rstd*slng[f0+1] + slnb[f0+1];
        float mx = fmaxf(sv0, sv1);
        mx = fmaxf(mx, __shfl_xor(mx,1,8));
        mx = fmaxf(mx, __shfl_xor(mx,2,8));
        mx = fmaxf(mx, __shfl_xor(mx,4,8));
        float e0 = __expf(sv0 - mx), e1 = __expf(sv1 - mx);
        float es = e0 + e1;
        es += __shfl_xor(es,1,8); es += __shfl_xor(es,2,8); es += __shfl_xor(es,4,8);
        float inv = 1.f / es;
        s_wsm[m*16 + f0]   = e0 * inv;
        s_wsm[m*16 + f0+1] = e1 * inv;
    }
    __syncthreads();

    // ---------------- pass 2: per-feature GRN + weighted sum ----------------
    float accV[8];
    #pragma unroll
    for (int i = 0; i < 8; i++) accV[i] = 0.f;

    for (int f = 0; f < 16; f++){
        {
            float xb = s_x[m*16 + f];
            #pragma unroll
            for (int i = 0; i < 8; i++)
                s_xp[m*65 + j0 + i] = xb * s_ipw[j0+i] + s_ipb[j0+i];
        }
        #pragma unroll
        for (int i = 0; i < 2; i++)
            ((float4*)s_W1)[tid + i*512] = *(const float4*)(vfc1w + f*4096 + (tid + i*512)*4);
        #pragma unroll
        for (int i = 0; i < 4; i++)
            ((float4*)s_W2)[tid + i*512] = *(const float4*)(vfc2w + f*8192 + (tid + i*512)*4);
        if (tid < 16)       ((float4*)s_b1)[tid]     = *(const float4*)(vfc1b + f*64  + tid*4);
        else if (tid < 48)  ((float4*)s_b2)[tid-16]  = *(const float4*)(vfc2b + f*128 + (tid-16)*4);
        else if (tid < 64)  ((float4*)s_lng)[tid-48] = *(const float4*)(vlng  + f*64  + (tid-48)*4);
        else if (tid < 80)  ((float4*)s_lnb)[tid-64] = *(const float4*)(vlnb  + f*64  + (tid-64)*4);
        __syncthreads();

        float ah[8];
        #pragma unroll
        for (int i = 0; i < 8; i++) ah[i] = 0.f;
        #pragma unroll 8
        for (int k = 0; k < 64; k++){
            float xv = s_xp[m*65 + k];
            const float4* wr = (const float4*)(s_W1 + k*64 + j0);
            float4 w0 = wr[0], w1 = wr[1];
            ah[0] += xv*w0.x; ah[1] += xv*w0.y; ah[2] += xv*w0.z; ah[3] += xv*w0.w;
            ah[4] += xv*w1.x; ah[5] += xv*w1.y; ah[6] += xv*w1.z; ah[7] += xv*w1.w;
        }
        #pragma unroll
        for (int i = 0; i < 8; i++)
            s_h[m*65 + j0 + i] = eluf(ah[i] + s_b1[j0+i]);
        __syncthreads();

        float aa[8], ag[8];
        #pragma unroll
        for (int i = 0; i < 8; i++){ aa[i] = 0.f; ag[i] = 0.f; }
        #pragma unroll 4
        for (int k = 0; k < 64; k++){
            float hv = s_h[m*65 + k];
            const float4* war = (const float4*)(s_W2 + k*128 + j0);
            const float4* wgr = (const float4*)(s_W2 + k*128 + 64 + j0);
            float4 wa0 = war[0], wa1 = war[1];
            float4 wg0 = wgr[0], wg1 = wgr[1];
            aa[0] += hv*wa0.x; aa[1] += hv*wa0.y; aa[2] += hv*wa0.z; aa[3] += hv*wa0.w;
            aa[4] += hv*wa1.x; aa[5] += hv*wa1.y; aa[6] += hv*wa1.z; aa[7] += hv*wa1.w;
            ag[0] += hv*wg0.x; ag[1] += hv*wg0.y; ag[2] += hv*wg0.z; ag[3] += hv*wg0.w;
            ag[4] += hv*wg1.x; ag[5] += hv*wg1.y; ag[6] += hv*wg1.z; ag[7] += hv*wg1.w;
        }
        float pre[8];
        float lsum = 0.f;
        #pragma unroll
        for (int i = 0; i < 8; i++){
            float av = aa[i] + s_b2[j0+i];
            float gv = ag[i] + s_b2[64 + j0+i];
            pre[i] = av * sigf(gv) + s_xp[m*65 + j0 + i];
            lsum += pre[i];
        }
        lsum += __shfl_xor(lsum,1,8); lsum += __shfl_xor(lsum,2,8); lsum += __shfl_xor(lsum,4,8);
        float mean = lsum * 0.015625f;
        float lvar = 0.f;
        #pragma unroll
        for (int i = 0; i < 8; i++){ float d = pre[i] - mean; lvar += d*d; }
        lvar += __shfl_xor(lvar,1,8); lvar += __shfl_xor(lvar,2,8); lvar += __shfl_xor(lvar,4,8);
        float rstd = rsqrtf(lvar * 0.015625f + 1e-5f);
        float wf = s_wsm[m*16 + f];
        #pragma unroll
        for (int i = 0; i < 8; i++)
            accV[i] += wf * ((pre[i] - mean) * rstd * s_lng[j0+i] + s_lnb[j0+i]);
        __syncthreads();
    }

    float4 o0 = make_float4(accV[0], accV[1], accV[2], accV[3]);
    float4 o1 = make_float4(accV[4], accV[5], accV[6], accV[7]);
    *(float4*)(vsn_out + (pos0 + m)*64 + j0)     = o0;
    *(float4*)(vsn_out + (pos0 + m)*64 + j0 + 4) = o1;
}

// ---------------------------------------------------------------------------
// Kernel 2: gpre = vsn_out @ w_ih[0] + b[0]   (unchanged)
// ---------------------------------------------------------------------------
__global__ __launch_bounds__(256) void tft_xgates_kernel(
    const float* __restrict__ vsn, const float* __restrict__ w_ih,
    const float* __restrict__ bias, float* __restrict__ gpre)
{
    __shared__ __align__(16) float s_w[64*256];
    __shared__ __align__(16) float s_vT[64*20];
    __shared__ __align__(16) float s_b[256];
    const int tid  = threadIdx.x;
    const int pos0 = blockIdx.x * 16;

    #pragma unroll
    for (int i = 0; i < 16; i++)
        ((float4*)s_w)[tid + i*256] = *(const float4*)(w_ih + (tid + i*256)*4);
    s_b[tid] = bias[tid];
    {
        int mm = tid >> 4;
        int k0 = (tid & 15) * 4;
        float4 v = *(const float4*)(vsn + (pos0 + mm)*64 + k0);
        s_vT[(k0+0)*20 + mm] = v.x;
        s_vT[(k0+1)*20 + mm] = v.y;
        s_vT[(k0+2)*20 + mm] = v.z;
        s_vT[(k0+3)*20 + mm] = v.w;
    }
    __syncthreads();

    float acc[16];
    #pragma unroll
    for (int i = 0; i < 16; i++) acc[i] = 0.f;
    #pragma unroll 8
    for (int k = 0; k < 64; k++){
        float wv = s_w[k*256 + tid];
        const float4* vr = (const float4*)(s_vT + k*20);
        float4 v0 = vr[0], v1 = vr[1], v2 = vr[2], v3 = vr[3];
        acc[0]  += wv*v0.x; acc[1]  += wv*v0.y; acc[2]  += wv*v0.z; acc[3]  += wv*v0.w;
        acc[4]  += wv*v1.x; acc[5]  += wv*v1.y; acc[6]  += wv*v1.z; acc[7]  += wv*v1.w;
        acc[8]  += wv*v2.x; acc[9]  += wv*v2.y; acc[10] += wv*v2.z; acc[11] += wv*v2.w;
        acc[12] += wv*v3.x; acc[13] += wv*v3.y; acc[14] += wv*v3.z; acc[15] += wv*v3.w;
    }
    float bv = s_b[tid];
    #pragma unroll
    for (int i = 0; i < 16; i++)
        gpre[(pos0 + i)*256 + tid] = acc[i] + bv;
}

// ---------------------------------------------------------------------------
// Kernel 3: 2-layer LSTM recurrence — EXACT round-4 version (best: 449 us).
// 512 threads (8 waves), 1 block/batch, K-split by 2, lagged L2, 2 lgkm-only
// barriers/step, weights in 24 named float4/thread, 2-deep gpre FIFO.
// ---------------------------------------------------------------------------
#define LDW4(P, i) make_float4((P)[(4*(i)+0)*256], (P)[(4*(i)+1)*256], \
                               (P)[(4*(i)+2)*256], (P)[(4*(i)+3)*256])

#define LSTM_CH(c) {                                                        \
    float4 h1c = h1b[c];                                                    \
    a10 += h1c.x*W1_##c.x; a11 += h1c.y*W1_##c.y;                           \
    a12 += h1c.z*W1_##c.z; a13 += h1c.w*W1_##c.w;                           \
    a20 += h1c.x*WX_##c.x; a21 += h1c.y*WX_##c.y;                           \
    a22 += h1c.z*WX_##c.z; a23 += h1c.w*WX_##c.w;                           \
    float4 h2c = h2b[c];                                                    \
    a20 += h2c.x*WH_##c.x; a21 += h2c.y*WH_##c.y;                           \
    a22 += h2c.z*WH_##c.z; a23 += h2c.w*WH_##c.w;                           \
}

__global__ __launch_bounds__(512, 1) void tft_lstm_kernel(
    const float* __restrict__ w_ih, const float* __restrict__ w_hh,
    const float* __restrict__ bias, const float* __restrict__ gpre,
    float* __restrict__ seq)
{
    __shared__ __align__(16) float s_h1[64];
    __shared__ __align__(16) float s_h2[64];
    __shared__ __align__(16) float s_g1h[512];   // [half][gate]
    __shared__ __align__(16) float s_g2h[512];
    __shared__ __align__(16) float s_gp[256];

    const int tid  = threadIdx.x;
    const int b    = blockIdx.x;
    const int g    = tid & 255;
    const int half = tid >> 8;       // wave-uniform (waves 0-3 vs 4-7)
    const int koff = half * 32;

    const float* p1 = w_hh + koff*256 + g;            // whh1[k][g], k in half range
    const float* px = w_ih + 16384 + koff*256 + g;    // wih2
    const float* ph = w_hh + 16384 + koff*256 + g;    // whh2

    float4 W1_0 = LDW4(p1,0), W1_1 = LDW4(p1,1), W1_2 = LDW4(p1,2), W1_3 = LDW4(p1,3);
    float4 W1_4 = LDW4(p1,4), W1_5 = LDW4(p1,5), W1_6 = LDW4(p1,6), W1_7 = LDW4(p1,7);
    float4 WX_0 = LDW4(px,0), WX_1 = LDW4(px,1), WX_2 = LDW4(px,2), WX_3 = LDW4(px,3);
    float4 WX_4 = LDW4(px,4), WX_5 = LDW4(px,5), WX_6 = LDW4(px,6), WX_7 = LDW4(px,7);
    float4 WH_0 = LDW4(ph,0), WH_1 = LDW4(ph,1), WH_2 = LDW4(ph,2), WH_3 = LDW4(ph,3);
    float4 WH_4 = LDW4(ph,4), WH_5 = LDW4(ph,5), WH_6 = LDW4(ph,6), WH_7 = LDW4(ph,7);

    const float b2 = (half == 0) ? bias[256 + g] : 0.f;   // L2 bias added once

    if (tid < 64) s_h1[tid] = 0.f;
    else if (tid < 128) s_h2[tid - 64] = 0.f;

    const float* gpb = gpre + (size_t)b * 512 * 256 + g;
    float gp_w = 0.f, gp_l = 0.f;
    if (half == 0){
        s_gp[g] = gpb[0];       // x-gates for t=0 (bias included)
        gp_w    = gpb[256];     // t=1 (published at ACT(0))
        gp_l    = gpb[512];     // t=2 (published at ACT(1))
    }
    float c1 = 0.f, c2 = 0.f;   // live in wave0 / wave1 lanes
    __syncthreads();

    const float4* h1b = (const float4*)s_h1 + half*8;
    const float4* h2b = (const float4*)s_h2 + half*8;
    float* seqb = seq + (size_t)b * 512 * 64;

    for (int n = 0; n <= 512; ++n){
        // ---- GATE phase: all 512 threads, half-dots ----
        float a10 = (half == 0) ? s_gp[g] : 0.f;
        float a11 = 0.f, a12 = 0.f, a13 = 0.f;     // L1 gate g, t=n
        float a20 = b2, a21 = 0.f, a22 = 0.f, a23 = 0.f;  // L2 gate g, t=n-1
        LSTM_CH(0) LSTM_CH(1) LSTM_CH(2) LSTM_CH(3)
        LSTM_CH(4) LSTM_CH(5) LSTM_CH(6) LSTM_CH(7)
        float gp_n = 0.f;
        if (half == 0 && n + 3 < 512) gp_n = gpb[(n + 3) * 256];  // 2-deep FIFO
        s_g1h[half*256 + g] = (a10 + a11) + (a12 + a13);
        s_g2h[half*256 + g] = (a20 + a21) + (a22 + a23);
        BARRIER_LGKM();

        // ---- ACT phase: wave0 -> L1 state; wave1 -> L2 state + seq store ----
        if (tid < 64 && n < 512){
            float gi = s_g1h[tid]     + s_g1h[256+tid];
            float gf = s_g1h[64+tid]  + s_g1h[320+tid];
            float gg = s_g1h[128+tid] + s_g1h[384+tid];
            float go = s_g1h[192+tid] + s_g1h[448+tid];
            c1 = sigf(gf)*c1 + sigf(gi)*tanhf_(gg);
            s_h1[tid] = sigf(go)*tanhf_(c1);
        } else if (tid >= 64 && tid < 128 && n >= 1){
            int j = tid - 64;
            float gi = s_g2h[j]     + s_g2h[256+j];
            float gf = s_g2h[64+j]  + s_g2h[320+j];
            float gg = s_g2h[128+j] + s_g2h[384+j];
            float go = s_g2h[192+j] + s_g2h[448+j];
            c2 = sigf(gf)*c2 + sigf(gi)*tanhf_(gg);
            float h2v = sigf(go)*tanhf_(c2);
            s_h2[j] = h2v;
            seqb[(size_t)(n - 1)*64 + j] = h2v;   // store ack never drained
        }
        if (half == 0 && n + 1 < 512) s_gp[g] = gp_w;  // publish t=n+1 x-gates
        gp_w = gp_l; gp_l = gp_n;
        BARRIER_LGKM();
    }
}

// ---------------------------------------------------------------------------
// Kernel 4: lo = LN(GLU(seq) + vsn_out); K,V; q/lo at t=T-1.  (unchanged)
// ---------------------------------------------------------------------------
__global__ __launch_bounds__(256) void tft_lokv_kernel(
    const float* __restrict__ seq, const float* __restrict__ vsn,
    const float* __restrict__ plgw, const float* __restrict__ plgb,
    const float* __restrict__ png,  const float* __restrict__ pnb,
    const float* __restrict__ qkvw, const float* __restrict__ qkvb,
    float* __restrict__ kbuf, float* __restrict__ vbuf,
    float* __restrict__ qlast, float* __restrict__ lolast)
{
    __shared__ __align__(16) float s_pw[64*128];
    __shared__ __align__(16) float s_qw[64*192];
    __shared__ __align__(16) float s_pb[128];
    __shared__ __align__(16) float s_png[64];
    __shared__ __align__(16) float s_pnb[64];
    __shared__ __align__(16) float s_qb[192];
    __shared__ __align__(16) float s_row[4][64];
    __shared__ __align__(16) float s_lo[4][64];

    const int tid  = threadIdx.x;
    const int lane = tid & 63;
    const int wid  = tid >> 6;

    #pragma unroll
    for (int i = 0; i < 8; i++)
        ((float4*)s_pw)[tid + i*256] = *(const float4*)(plgw + (tid + i*256)*4);
    #pragma unroll
    for (int i = 0; i < 12; i++)
        ((float4*)s_qw)[tid + i*256] = *(const float4*)(qkvw + (tid + i*256)*4);
    if (tid < 128) s_pb[tid] = plgb[tid];
    if (tid < 64){ s_png[tid] = png[tid]; s_pnb[tid] = pnb[tid]; }
    if (tid < 192) s_qb[tid] = qkvb[tid];
    __syncthreads();

    for (int it = 0; it < 16; it++){
        int mpos = blockIdx.x*64 + wid*16 + it;
        int b = mpos >> 9, t = mpos & 511;
        float sv = seq[mpos*64 + lane];
        float vs = vsn[mpos*64 + lane];
        s_row[wid][lane] = sv;
        __syncthreads();
        float a = s_pb[lane], g = s_pb[64 + lane];
        #pragma unroll 8
        for (int k = 0; k < 64; k++){
            float rv = s_row[wid][k];
            a += rv * s_pw[k*128 + lane];
            g += rv * s_pw[k*128 + 64 + lane];
        }
        float pre = a * sigf(g) + vs;
        float mean = wsum64(pre) * 0.015625f;
        float d = pre - mean;
        float vv = wsum64(d*d) * 0.015625f;
        float lo = d * rsqrtf(vv + 1e-5f) * s_png[lane] + s_pnb[lane];
        s_lo[wid][lane] = lo;
        __syncthreads();
        float ka = s_qb[64 + lane], va = s_qb[128 + lane];
        #pragma unroll 8
        for (int k = 0; k < 64; k++){
            float lv = s_lo[wid][k];
            ka += lv * s_qw[k*192 + 64 + lane];
            va += lv * s_qw[k*192 + 128 + lane];
        }
        int h = lane >> 4, dd = lane & 15;
        kbuf[((b*4 + h)*512 + t)*16 + dd] = ka;
        vbuf[((b*4 + h)*512 + t)*16 + dd] = va;
        if (t == 511){
            float qa = s_qb[lane];
            #pragma unroll 8
            for (int k = 0; k < 64; k++)
                qa += s_lo[wid][k] * s_qw[k*192 + lane];
            qlast[b*64 + lane] = qa;
            lolast[b*64 + lane] = lo;
        }
    }
}

// ---------------------------------------------------------------------------
// Kernel 5: head (attention at t=T-1 + GRNs + out).  (unchanged)
// ---------------------------------------------------------------------------
__global__ __launch_bounds__(256) void tft_head_kernel(
    const float* __restrict__ kbuf, const float* __restrict__ vbuf,
    const float* __restrict__ qlast, const float* __restrict__ lolast,
    const float* __restrict__ aow,  const float* __restrict__ aob,
    const float* __restrict__ pagw, const float* __restrict__ pagb,
    const float* __restrict__ pang, const float* __restrict__ panb,
    const float* __restrict__ ff1w, const float* __restrict__ ff1b,
    const float* __restrict__ ff2w, const float* __restrict__ ff2b,
    const float* __restrict__ fflng, const float* __restrict__ fflnb,
    const float* __restrict__ fng,  const float* __restrict__ fnb,
    const float* __restrict__ outw, const float* __restrict__ outb,
    float* __restrict__ out)
{
    __shared__ __align__(16) float s_q[64];
    __shared__ __align__(16) float s_lo[64];
    __shared__ __align__(16) float s_sc[4*512];
    __shared__ __align__(16) float s_part[4][64];
    __shared__ __align__(16) float s_a[64];
    __shared__ __align__(16) float s_a2[64];
    __shared__ __align__(16) float s_z[128];
    __shared__ __align__(16) float s_at[64];
    __shared__ __align__(16) float s_f1[256];

    const int tid = threadIdx.x;
    const int b   = blockIdx.x;
    if (tid < 64){ s_q[tid] = qlast[b*64 + tid]; s_lo[tid] = lolast[b*64 + tid]; }
    __syncthreads();

    for (int idx = tid; idx < 2048; idx += 256){
        int h = idx >> 9, t = idx & 511;
        const float4* kr = (const float4*)(kbuf + ((b*4 + h)*512 + t)*16);
        const float4* qr = (const float4*)(s_q + h*16);
        float4 k0 = kr[0], k1 = kr[1], k2 = kr[2], k3 = kr[3];
        float4 q0 = qr[0], q1 = qr[1], q2 = qr[2], q3 = qr[3];
        float d = q0.x*k0.x + q0.y*k0.y + q0.z*k0.z + q0.w*k0.w
                + q1.x*k1.x + q1.y*k1.y + q1.z*k1.z + q1.w*k1.w
                + q2.x*k2.x + q2.y*k2.y + q2.z*k2.z + q2.w*k2.w
                + q3.x*k3.x + q3.y*k3.y + q3.z*k3.z + q3.w*k3.w;
        s_sc[idx] = d * 0.25f;
    }
    __syncthreads();
    {
        int h = tid >> 6, lane = tid & 63;
        float v[8];
        float mx = -1e30f;
        #pragma unroll
        for (int j = 0; j < 8; j++){ v[j] = s_sc[h*512 + lane + j*64]; mx = fmaxf(mx, v[j]); }
        mx = wmax64(mx);
        float sum = 0.f;
        #pragma unroll
        for (int j = 0; j < 8; j++){ v[j] = __expf(v[j] - mx); sum += v[j]; }
        sum = wsum64(sum);
        float inv = 1.f / sum;
        #pragma unroll
        for (int j = 0; j < 8; j++) s_sc[h*512 + lane + j*64] = v[j] * inv;
    }
    __syncthreads();
    {
        int j = tid & 63, part = tid >> 6;
        int h = j >> 4, dd = j & 15;
        float pa = 0.f;
        for (int t = part*128; t < (part+1)*128; t++)
            pa += s_sc[h*512 + t] * vbuf[((b*4 + h)*512 + t)*16 + dd];
        s_part[part][j] = pa;
    }
    __syncthreads();
    if (tid < 64) s_a[tid] = s_part[0][tid] + s_part[1][tid] + s_part[2][tid] + s_part[3][tid];
    __syncthreads();
    if (tid < 64){
        float o = aob[tid];
        #pragma unroll 8
        for (int k = 0; k < 64; k++) o += s_a[k] * aow[k*64 + tid];
        s_a2[tid] = o;
    }
    __syncthreads();
    if (tid < 128){
        float z = pagb[tid];
        #pragma unroll 8
        for (int k = 0; k < 64; k++) z += s_a2[k] * pagw[k*128 + tid];
        s_z[tid] = z;
    }
    __syncthreads();
    if (tid < 64){
        float pre = s_z[tid] * sigf(s_z[64 + tid]) + s_lo[tid];
        float mean = wsum64(pre) * 0.015625f;
        float d = pre - mean;
        float vv = wsum64(d*d) * 0.015625f;
        s_at[tid] = d * rsqrtf(vv + 1e-5f) * pang[tid] + panb[tid];
    }
    __syncthreads();
    {
        float hv = ff1b[tid];
        #pragma unroll 8
        for (int k = 0; k < 64; k++) hv += s_at[k] * ff1w[k*256 + tid];
        s_f1[tid] = eluf(hv);
    }
    __syncthreads();
    if (tid < 128){
        float z = ff2b[tid];
        #pragma unroll 8
        for (int k = 0; k < 256; k++) z += s_f1[k] * ff2w[k*128 + tid];
        s_z[tid] = z;
    }
    __syncthreads();
    if (tid < 64){
        float pre = s_z[tid] * sigf(s_z[64 + tid]) + s_at[tid];
        float mean = wsum64(pre) * 0.015625f;
        float d = pre - mean;
        float vv = wsum64(d*d) * 0.015625f;
        float ffv = d * rsqrtf(vv + 1e-5f) * fflng[tid] + fflnb[tid];
        float pre2 = ffv + s_at[tid];
        float mean2 = wsum64(pre2) * 0.015625f;
        float d2 = pre2 - mean2;
        float v2 = wsum64(d2*d2) * 0.015625f;
        float f2 = d2 * rsqrtf(v2 + 1e-5f) * fng[tid] + fnb[tid];
        float p = wsum64(f2 * outw[tid]);
        if (tid == 0) out[b] = p + outb[0];
    }
}

// ---------------------------------------------------------------------------
extern "C" void kernel_launch(void* const* d_in, const int* in_sizes, int n_in,
                              void* d_out, int out_size, void* d_ws, size_t ws_size,
                              hipStream_t stream)
{
    const float* x     = (const float*)d_in[0];
    const float* ip_w  = (const float*)d_in[1];
    const float* ip_b  = (const float*)d_in[2];
    const float* vfc1w = (const float*)d_in[3];
    const float* vfc1b = (const float*)d_in[4];
    const float* vfc2w = (const float*)d_in[5];
    const float* vfc2b = (const float*)d_in[6];
    const float* vlng  = (const float*)d_in[7];
    const float* vlnb  = (const float*)d_in[8];
    const float* sfc1w = (const float*)d_in[9];
    const float* sfc1b = (const float*)d_in[10];
    const float* sfc2w = (const float*)d_in[11];
    const float* sfc2b = (const float*)d_in[12];
    const float* sskw  = (const float*)d_in[13];
    const float* sskb  = (const float*)d_in[14];
    const float* slng  = (const float*)d_in[15];
    const float* slnb  = (const float*)d_in[16];
    const float* lwih  = (const float*)d_in[17];
    const float* lwhh  = (const float*)d_in[18];
    const float* lb    = (const float*)d_in[19];
    const float* plgw  = (const float*)d_in[20];
    const float* plgb  = (const float*)d_in[21];
    const float* plng  = (const float*)d_in[22];
    const float* plnb  = (const float*)d_in[23];
    const float* qkvw  = (const float*)d_in[24];
    const float* qkvb  = (const float*)d_in[25];
    const float* aow   = (const float*)d_in[26];
    const float* aob   = (const float*)d_in[27];
    const float* pagw  = (const float*)d_in[28];
    const float* pagb  = (const float*)d_in[29];
    const float* pang  = (const float*)d_in[30];
    const float* panb  = (const float*)d_in[31];
    const float* ff1w  = (const float*)d_in[32];
    const float* ff1b  = (const float*)d_in[33];
    const float* ff2w  = (const float*)d_in[34];
    const float* ff2b  = (const float*)d_in[35];
    const float* fflng = (const float*)d_in[36];
    const float* fflnb = (const float*)d_in[37];
    const float* fng   = (const float*)d_in[38];
    const float* fnb   = (const float*)d_in[39];
    const float* outw  = (const float*)d_in[40];
    const float* outb  = (const float*)d_in[41];

    float* ws      = (float*)d_ws;
    float* vsn_out = ws;                    // 16384*64    = 1,048,576 f
    float* seq     = ws + 1048576;          // 16384*64    = 1,048,576 f
    float* gpre    = ws + 2*1048576;        // 16384*256   = 4,194,304 f
    float* kbuf    = ws + 6*1048576;        // 32*4*512*16 = 1,048,576 f
    float* vbuf    = ws + 7*1048576;        // 1,048,576 f
    float* qlast   = ws + 8*1048576;        // 2048 f
    float* lolast  = qlast + 2048;          // 2048 f
    float* outp    = (float*)d_out;

    tft_vsn_kernel<<<256, 512, 0, stream>>>(x, ip_w, ip_b, vfc1w, vfc1b, vfc2w, vfc2b,
                                            vlng, vlnb, sfc1w, sfc1b, sfc2w, sfc2b,
                                            sskw, sskb, slng, slnb, vsn_out);
    tft_xgates_kernel<<<1024, 256, 0, stream>>>(vsn_out, lwih, lb, gpre);
    tft_lstm_kernel<<<32, 512, 0, stream>>>(lwih, lwhh, lb, gpre, seq);
    tft_lokv_kernel<<<256, 256, 0, stream>>>(seq, vsn_out, plgw, plgb, plng, plnb,
                                             qkvw, qkvb, kbuf, vbuf, qlast, lolast);
    tft_head_kernel<<<32, 256, 0, stream>>>(kbuf, vbuf, qlast, lolast, aow, aob,
                                            pagw, pagb, pang, panb, ff1w, ff1b,
                                            ff2w, ff2b, fflng, fflnb, fng, fnb,
                                            outw, outb, outp);
}

// Round 14
// 696.641 us; speedup vs baseline: 1.4341x; 1.0987x over previous
//
#include <hip/hip_runtime.h>
#include <math.h>

// Problem dims: B=32, T=512, F=16, H=64, NH=4, HD=16, L=2.  BT=16384.

typedef __fp16 half2_t __attribute__((ext_vector_type(2)));
union h2u_t { unsigned u; half2_t h; };
__device__ __forceinline__ half2_t u2h(unsigned u){ h2u_t x; x.u = u; return x.h; }
__device__ __forceinline__ unsigned h2u(half2_t h){ h2u_t x; x.h = h; return x.u; }

__device__ __forceinline__ float sigf(float x){
    return 1.f / (1.f + __expf(-x));
}
__device__ __forceinline__ float tanhf_(float x){
    float xc = fminf(fmaxf(x, -15.f), 15.f);   // clamp: avoid inf/inf NaN
    float e = __expf(-2.f * xc);
    return (1.f - e) / (1.f + e);
}
__device__ __forceinline__ float eluf(float x){
    return x > 0.f ? x : (__expf(x) - 1.f);
}
__device__ __forceinline__ float wsum64(float v){
    #pragma unroll
    for (int o = 1; o < 64; o <<= 1) v += __shfl_xor(v, o, 64);
    return v;
}
__device__ __forceinline__ float wmax64(float v){
    #pragma unroll
    for (int o = 1; o < 64; o <<= 1) v = fmaxf(v, __shfl_xor(v, o, 64));
    return v;
}

// Barrier that waits only for LDS ops (NOT vmcnt) — global stores/loads stay
// in flight across it (__syncthreads would drain vmcnt(0)).
#define BARRIER_LGKM() do {                                    \
    asm volatile("s_waitcnt lgkmcnt(0)" ::: "memory");         \
    __builtin_amdgcn_s_barrier();                              \
} while(0)

// ---------------------------------------------------------------------------
// Kernel 1: VSN v2 — 64 positions/block, 512 threads, 256 blocks. (r12)
// ---------------------------------------------------------------------------
__global__ __launch_bounds__(512) void tft_vsn_kernel(
    const float* __restrict__ x,
    const float* __restrict__ ip_w, const float* __restrict__ ip_b,
    const float* __restrict__ vfc1w, const float* __restrict__ vfc1b,
    const float* __restrict__ vfc2w, const float* __restrict__ vfc2b,
    const float* __restrict__ vlng, const float* __restrict__ vlnb,
    const float* __restrict__ sfc1w, const float* __restrict__ sfc1b,
    const float* __restrict__ sfc2w, const float* __restrict__ sfc2b,
    const float* __restrict__ sskw, const float* __restrict__ sskb,
    const float* __restrict__ slng, const float* __restrict__ slnb,
    float* __restrict__ vsn_out)
{
    __shared__ __align__(16) float s_x[64*16];
    __shared__ __align__(16) float s_ipw[64];
    __shared__ __align__(16) float s_ipb[64];
    __shared__ __align__(16) float s_xp[64*65];
    __shared__ __align__(16) float s_W1[64*64];
    __shared__ __align__(16) float s_W2[64*128];
    __shared__ __align__(16) float s_Wsk[64*16];
    __shared__ __align__(16) float s_h[64*65];
    __shared__ __align__(16) float s_sel2[64*32];
    __shared__ __align__(16) float s_wsm[64*16];
    __shared__ __align__(16) float s_lng[64];
    __shared__ __align__(16) float s_lnb[64];
    __shared__ __align__(16) float s_b1[64];
    __shared__ __align__(16) float s_b2[128];

    const int tid  = threadIdx.x;
    const int pos0 = blockIdx.x * 64;
    const int m    = tid >> 3;
    const int g8   = tid & 7;
    const int j0   = g8 * 8;

    if (tid < 256) ((float4*)s_x)[tid] = *(const float4*)(x + pos0*16 + tid*4);
    if (tid < 64) { s_ipw[tid] = ip_w[tid]; s_ipb[tid] = ip_b[tid]; }
    __syncthreads();

    float accS[8];
    #pragma unroll
    for (int i = 0; i < 8; i++) accS[i] = 0.f;
    float accK0 = 0.f, accK1 = 0.f;

    for (int f = 0; f < 16; f++){
        {
            float xb = s_x[m*16 + f];
            #pragma unroll
            for (int i = 0; i < 8; i++)
                s_xp[m*65 + j0 + i] = xb * s_ipw[j0+i] + s_ipb[j0+i];
        }
        #pragma unroll
        for (int i = 0; i < 2; i++)
            ((float4*)s_W1)[tid + i*512] = *(const float4*)(sfc1w + f*4096 + (tid + i*512)*4);
        if (tid < 256) ((float4*)s_Wsk)[tid] = *(const float4*)(sskw + f*1024 + tid*4);
        __syncthreads();
        #pragma unroll 8
        for (int k = 0; k < 64; k++){
            float xv = s_xp[m*65 + k];
            const float4* wr = (const float4*)(s_W1 + k*64 + j0);
            float4 w0 = wr[0], w1 = wr[1];
            accS[0] += xv*w0.x; accS[1] += xv*w0.y; accS[2] += xv*w0.z; accS[3] += xv*w0.w;
            accS[4] += xv*w1.x; accS[5] += xv*w1.y; accS[6] += xv*w1.z; accS[7] += xv*w1.w;
            float2 wk = *(const float2*)(s_Wsk + k*16 + g8*2);
            accK0 += xv*wk.x; accK1 += xv*wk.y;
        }
        __syncthreads();
    }

    #pragma unroll
    for (int i = 0; i < 8; i++)
        s_h[m*65 + j0 + i] = eluf(accS[i] + sfc1b[j0+i]);
    ((float4*)s_W1)[tid] = *(const float4*)(sfc2w + tid*4);
    __syncthreads();

    {
        const int jj = g8 * 4;
        float a0 = 0.f, a1 = 0.f, a2 = 0.f, a3 = 0.f;
        #pragma unroll 8
        for (int k = 0; k < 64; k++){
            float hv = s_h[m*65 + k];
            float4 w = *(const float4*)(s_W1 + k*32 + jj);
            a0 += hv*w.x; a1 += hv*w.y; a2 += hv*w.z; a3 += hv*w.w;
        }
        s_sel2[m*32 + jj+0] = a0 + sfc2b[jj+0];
        s_sel2[m*32 + jj+1] = a1 + sfc2b[jj+1];
        s_sel2[m*32 + jj+2] = a2 + sfc2b[jj+2];
        s_sel2[m*32 + jj+3] = a3 + sfc2b[jj+3];
    }
    __syncthreads();

    {
        const int f0 = g8 * 2;
        float a0 = s_sel2[m*32 + f0],   g0 = s_sel2[m*32 + 16 + f0];
        float a1 = s_sel2[m*32 + f0+1], g1 = s_sel2[m*32 + 16 + f0+1];
        float pre0 = a0*sigf(g0) + accK0 + sskb[f0];
        float pre1 = a1*sigf(g1) + accK1 + sskb[f0+1];
        float sum = pre0 + pre1;
        sum += __shfl_xor(sum,1,8); sum += __shfl_xor(sum,2,8); sum += __shfl_xor(sum,4,8);
        float mean = sum * 0.0625f;
        float d0 = pre0 - mean, d1 = pre1 - mean;
        float vv = d0*d0 + d1*d1;
        vv += __shfl_xor(vv,1,8); vv += __shfl_xor(vv,2,8); vv += __shfl_xor(vv,4,8);
        float rstd = rsqrtf(vv * 0.0625f + 1e-5f);
        float sv0 = d0*rstd*slng[f0]   + slnb[f0];
        float sv1 = d1*rstd*slng[f0+1] + slnb[f0+1];
        float mx = fmaxf(sv0, sv1);
        mx = fmaxf(mx, __shfl_xor(mx,1,8));
        mx = fmaxf(mx, __shfl_xor(mx,2,8));
        mx = fmaxf(mx, __shfl_xor(mx,4,8));
        float e0 = __expf(sv0 - mx), e1 = __expf(sv1 - mx);
        float es = e0 + e1;
        es += __shfl_xor(es,1,8); es += __shfl_xor(es,2,8); es += __shfl_xor(es,4,8);
        float inv = 1.f / es;
        s_wsm[m*16 + f0]   = e0 * inv;
        s_wsm[m*16 + f0+1] = e1 * inv;
    }
    __syncthreads();

    float accV[8];
    #pragma unroll
    for (int i = 0; i < 8; i++) accV[i] = 0.f;

    for (int f = 0; f < 16; f++){
        {
            float xb = s_x[m*16 + f];
            #pragma unroll
            for (int i = 0; i < 8; i++)
                s_xp[m*65 + j0 + i] = xb * s_ipw[j0+i] + s_ipb[j0+i];
        }
        #pragma unroll
        for (int i = 0; i < 2; i++)
            ((float4*)s_W1)[tid + i*512] = *(const float4*)(vfc1w + f*4096 + (tid + i*512)*4);
        #pragma unroll
        for (int i = 0; i < 4; i++)
            ((float4*)s_W2)[tid + i*512] = *(const float4*)(vfc2w + f*8192 + (tid + i*512)*4);
        if (tid < 16)       ((float4*)s_b1)[tid]     = *(const float4*)(vfc1b + f*64  + tid*4);
        else if (tid < 48)  ((float4*)s_b2)[tid-16]  = *(const float4*)(vfc2b + f*128 + (tid-16)*4);
        else if (tid < 64)  ((float4*)s_lng)[tid-48] = *(const float4*)(vlng  + f*64  + (tid-48)*4);
        else if (tid < 80)  ((float4*)s_lnb)[tid-64] = *(const float4*)(vlnb  + f*64  + (tid-64)*4);
        __syncthreads();

        float ah[8];
        #pragma unroll
        for (int i = 0; i < 8; i++) ah[i] = 0.f;
        #pragma unroll 8
        for (int k = 0; k < 64; k++){
            float xv = s_xp[m*65 + k];
            const float4* wr = (const float4*)(s_W1 + k*64 + j0);
            float4 w0 = wr[0], w1 = wr[1];
            ah[0] += xv*w0.x; ah[1] += xv*w0.y; ah[2] += xv*w0.z; ah[3] += xv*w0.w;
            ah[4] += xv*w1.x; ah[5] += xv*w1.y; ah[6] += xv*w1.z; ah[7] += xv*w1.w;
        }
        #pragma unroll
        for (int i = 0; i < 8; i++)
            s_h[m*65 + j0 + i] = eluf(ah[i] + s_b1[j0+i]);
        __syncthreads();

        float aa[8], ag[8];
        #pragma unroll
        for (int i = 0; i < 8; i++){ aa[i] = 0.f; ag[i] = 0.f; }
        #pragma unroll 4
        for (int k = 0; k < 64; k++){
            float hv = s_h[m*65 + k];
            const float4* war = (const float4*)(s_W2 + k*128 + j0);
            const float4* wgr = (const float4*)(s_W2 + k*128 + 64 + j0);
            float4 wa0 = war[0], wa1 = war[1];
            float4 wg0 = wgr[0], wg1 = wgr[1];
            aa[0] += hv*wa0.x; aa[1] += hv*wa0.y; aa[2] += hv*wa0.z; aa[3] += hv*wa0.w;
            aa[4] += hv*wa1.x; aa[5] += hv*wa1.y; aa[6] += hv*wa1.z; aa[7] += hv*wa1.w;
            ag[0] += hv*wg0.x; ag[1] += hv*wg0.y; ag[2] += hv*wg0.z; ag[3] += hv*wg0.w;
            ag[4] += hv*wg1.x; ag[5] += hv*wg1.y; ag[6] += hv*wg1.z; ag[7] += hv*wg1.w;
        }
        float pre[8];
        float lsum = 0.f;
        #pragma unroll
        for (int i = 0; i < 8; i++){
            float av = aa[i] + s_b2[j0+i];
            float gv = ag[i] + s_b2[64 + j0+i];
            pre[i] = av * sigf(gv) + s_xp[m*65 + j0 + i];
            lsum += pre[i];
        }
        lsum += __shfl_xor(lsum,1,8); lsum += __shfl_xor(lsum,2,8); lsum += __shfl_xor(lsum,4,8);
        float mean = lsum * 0.015625f;
        float lvar = 0.f;
        #pragma unroll
        for (int i = 0; i < 8; i++){ float d = pre[i] - mean; lvar += d*d; }
        lvar += __shfl_xor(lvar,1,8); lvar += __shfl_xor(lvar,2,8); lvar += __shfl_xor(lvar,4,8);
        float rstd = rsqrtf(lvar * 0.015625f + 1e-5f);
        float wf = s_wsm[m*16 + f];
        #pragma unroll
        for (int i = 0; i < 8; i++)
            accV[i] += wf * ((pre[i] - mean) * rstd * s_lng[j0+i] + s_lnb[j0+i]);
        __syncthreads();
    }

    float4 o0 = make_float4(accV[0], accV[1], accV[2], accV[3]);
    float4 o1 = make_float4(accV[4], accV[5], accV[6], accV[7]);
    *(float4*)(vsn_out + (pos0 + m)*64 + j0)     = o0;
    *(float4*)(vsn_out + (pos0 + m)*64 + j0 + 4) = o1;
}

// ---------------------------------------------------------------------------
// Kernel 2: gpre = vsn_out @ w_ih[0] + b[0]   (unchanged)
// ---------------------------------------------------------------------------
__global__ __launch_bounds__(256) void tft_xgates_kernel(
    const float* __restrict__ vsn, const float* __restrict__ w_ih,
    const float* __restrict__ bias, float* __restrict__ gpre)
{
    __shared__ __align__(16) float s_w[64*256];
    __shared__ __align__(16) float s_vT[64*20];
    __shared__ __align__(16) float s_b[256];
    const int tid  = threadIdx.x;
    const int pos0 = blockIdx.x * 16;

    #pragma unroll
    for (int i = 0; i < 16; i++)
        ((float4*)s_w)[tid + i*256] = *(const float4*)(w_ih + (tid + i*256)*4);
    s_b[tid] = bias[tid];
    {
        int mm = tid >> 4;
        int k0 = (tid & 15) * 4;
        float4 v = *(const float4*)(vsn + (pos0 + mm)*64 + k0);
        s_vT[(k0+0)*20 + mm] = v.x;
        s_vT[(k0+1)*20 + mm] = v.y;
        s_vT[(k0+2)*20 + mm] = v.z;
        s_vT[(k0+3)*20 + mm] = v.w;
    }
    __syncthreads();

    float acc[16];
    #pragma unroll
    for (int i = 0; i < 16; i++) acc[i] = 0.f;
    #pragma unroll 8
    for (int k = 0; k < 64; k++){
        float wv = s_w[k*256 + tid];
        const float4* vr = (const float4*)(s_vT + k*20);
        float4 v0 = vr[0], v1 = vr[1], v2 = vr[2], v3 = vr[3];
        acc[0]  += wv*v0.x; acc[1]  += wv*v0.y; acc[2]  += wv*v0.z; acc[3]  += wv*v0.w;
        acc[4]  += wv*v1.x; acc[5]  += wv*v1.y; acc[6]  += wv*v1.z; acc[7]  += wv*v1.w;
        acc[8]  += wv*v2.x; acc[9]  += wv*v2.y; acc[10] += wv*v2.z; acc[11] += wv*v2.w;
        acc[12] += wv*v3.x; acc[13] += wv*v3.y; acc[14] += wv*v3.z; acc[15] += wv*v3.w;
    }
    float bv = s_b[tid];
    #pragma unroll
    for (int i = 0; i < 16; i++)
        gpre[(pos0 + i)*256 + tid] = acc[i] + bv;
}

// ---------------------------------------------------------------------------
// Kernel 3: 2-layer LSTM — round-14 (= r13 with the typedef fixed):
// f16-packed weights + v_dot2_f32_f16.  r4 skeleton (512 thr, K-split by 2,
// lagged L2, 2 lgkm-only barriers/step); 96 fp32 weights/thread -> 48 half2
// registers (~88 VGPR total need < the ~100 grant -> no sinking/refetch).
// h stored in LDS pre-packed as half2 by ACT writers (cvt_pkrtz + shfl),
// read back as wave-uniform uint2 broadcasts.  GATE = 48 fdot2/thread.
// ---------------------------------------------------------------------------
#define PKW(P, r) __builtin_amdgcn_cvt_pkrtz((P)[(2*(r))*256], (P)[(2*(r)+1)*256])

#define LSTM_CH(c) {                                                        \
    uint2 q1 = h1q[c];                                                      \
    half2_t h01 = u2h(q1.x), h23 = u2h(q1.y);                               \
    a10 = __builtin_amdgcn_fdot2(W1_##c##a, h01, a10, false);               \
    a11 = __builtin_amdgcn_fdot2(W1_##c##b, h23, a11, false);               \
    a20 = __builtin_amdgcn_fdot2(WX_##c##a, h01, a20, false);               \
    a21 = __builtin_amdgcn_fdot2(WX_##c##b, h23, a21, false);               \
    uint2 q2 = h2q[c];                                                      \
    half2_t g01 = u2h(q2.x), g23 = u2h(q2.y);                               \
    a22 = __builtin_amdgcn_fdot2(WH_##c##a, g01, a22, false);               \
    a23 = __builtin_amdgcn_fdot2(WH_##c##b, g23, a23, false);               \
}

__global__ __launch_bounds__(512, 1) void tft_lstm_kernel(
    const float* __restrict__ w_ih, const float* __restrict__ w_hh,
    const float* __restrict__ bias, const float* __restrict__ gpre,
    float* __restrict__ seq)
{
    __shared__ __align__(16) unsigned s_h1p[32];   // h1 packed half2 pairs
    __shared__ __align__(16) unsigned s_h2p[32];   // h2 packed half2 pairs
    __shared__ __align__(16) float s_g1h[512];     // [half][gate]
    __shared__ __align__(16) float s_g2h[512];
    __shared__ __align__(16) float s_gp[256];

    const int tid  = threadIdx.x;
    const int b    = blockIdx.x;
    const int g    = tid & 255;
    const int half = tid >> 8;       // wave-uniform (waves 0-3 vs 4-7)
    const int koff = half * 32;

    const float* p1 = w_hh + koff*256 + g;            // whh1[k][g], k in half range
    const float* px = w_ih + 16384 + koff*256 + g;    // wih2
    const float* ph = w_hh + 16384 + koff*256 + g;    // whh2

    half2_t W1_0a = PKW(p1,0),  W1_0b = PKW(p1,1),  W1_1a = PKW(p1,2),  W1_1b = PKW(p1,3);
    half2_t W1_2a = PKW(p1,4),  W1_2b = PKW(p1,5),  W1_3a = PKW(p1,6),  W1_3b = PKW(p1,7);
    half2_t W1_4a = PKW(p1,8),  W1_4b = PKW(p1,9),  W1_5a = PKW(p1,10), W1_5b = PKW(p1,11);
    half2_t W1_6a = PKW(p1,12), W1_6b = PKW(p1,13), W1_7a = PKW(p1,14), W1_7b = PKW(p1,15);
    half2_t WX_0a = PKW(px,0),  WX_0b = PKW(px,1),  WX_1a = PKW(px,2),  WX_1b = PKW(px,3);
    half2_t WX_2a = PKW(px,4),  WX_2b = PKW(px,5),  WX_3a = PKW(px,6),  WX_3b = PKW(px,7);
    half2_t WX_4a = PKW(px,8),  WX_4b = PKW(px,9),  WX_5a = PKW(px,10), WX_5b = PKW(px,11);
    half2_t WX_6a = PKW(px,12), WX_6b = PKW(px,13), WX_7a = PKW(px,14), WX_7b = PKW(px,15);
    half2_t WH_0a = PKW(ph,0),  WH_0b = PKW(ph,1),  WH_1a = PKW(ph,2),  WH_1b = PKW(ph,3);
    half2_t WH_2a = PKW(ph,4),  WH_2b = PKW(ph,5),  WH_3a = PKW(ph,6),  WH_3b = PKW(ph,7);
    half2_t WH_4a = PKW(ph,8),  WH_4b = PKW(ph,9),  WH_5a = PKW(ph,10), WH_5b = PKW(ph,11);
    half2_t WH_6a = PKW(ph,12), WH_6b = PKW(ph,13), WH_7a = PKW(ph,14), WH_7b = PKW(ph,15);

    const float b2 = (half == 0) ? bias[256 + g] : 0.f;   // L2 bias added once

    if (tid < 32) s_h1p[tid] = 0u;
    else if (tid < 64) s_h2p[tid - 32] = 0u;

    const float* gpb = gpre + (size_t)b * 512 * 256 + g;
    float gp_w = 0.f, gp_l = 0.f;
    if (half == 0){
        s_gp[g] = gpb[0];       // x-gates for t=0 (bias included)
        gp_w    = gpb[256];     // t=1 (published at ACT(0))
        gp_l    = gpb[512];     // t=2 (published at ACT(1))
    }
    float c1 = 0.f, c2 = 0.f;   // live in wave0 / wave1 lanes
    __syncthreads();

    const uint2* h1q = (const uint2*)s_h1p + half*8;
    const uint2* h2q = (const uint2*)s_h2p + half*8;
    float* seqb = seq + (size_t)b * 512 * 64;

    for (int n = 0; n <= 512; ++n){
        // ---- GATE phase: all 512 threads, half-dots via fdot2 ----
        float a10 = (half == 0) ? s_gp[g] : 0.f;
        float a11 = 0.f;                                   // L1 gate g, t=n
        float a20 = b2, a21 = 0.f, a22 = 0.f, a23 = 0.f;   // L2 gate g, t=n-1
        LSTM_CH(0) LSTM_CH(1) LSTM_CH(2) LSTM_CH(3)
        LSTM_CH(4) LSTM_CH(5) LSTM_CH(6) LSTM_CH(7)
        float gp_n = 0.f;
        if (half == 0 && n + 3 < 512) gp_n = gpb[(n + 3) * 256];  // 2-deep FIFO
        s_g1h[half*256 + g] = a10 + a11;
        s_g2h[half*256 + g] = (a20 + a21) + (a22 + a23);
        BARRIER_LGKM();

        // ---- ACT phase: wave0 -> L1 state; wave1 -> L2 state + seq store ----
        if (tid < 64 && n < 512){
            float gi = s_g1h[tid]     + s_g1h[256+tid];
            float gf = s_g1h[64+tid]  + s_g1h[320+tid];
            float gg = s_g1h[128+tid] + s_g1h[384+tid];
            float go = s_g1h[192+tid] + s_g1h[448+tid];
            c1 = sigf(gf)*c1 + sigf(gi)*tanhf_(gg);
            float h1v = sigf(go)*tanhf_(c1);
            float hn = __shfl_xor(h1v, 1, 64);
            if ((tid & 1) == 0)
                s_h1p[tid >> 1] = h2u(__builtin_amdgcn_cvt_pkrtz(h1v, hn));
        } else if (tid >= 64 && tid < 128 && n >= 1){
            int j = tid - 64;
            float gi = s_g2h[j]     + s_g2h[256+j];
            float gf = s_g2h[64+j]  + s_g2h[320+j];
            float gg = s_g2h[128+j] + s_g2h[384+j];
            float go = s_g2h[192+j] + s_g2h[448+j];
            c2 = sigf(gf)*c2 + sigf(gi)*tanhf_(gg);
            float h2v = sigf(go)*tanhf_(c2);
            float hn = __shfl_xor(h2v, 1, 64);
            if ((j & 1) == 0)
                s_h2p[j >> 1] = h2u(__builtin_amdgcn_cvt_pkrtz(h2v, hn));
            seqb[(size_t)(n - 1)*64 + j] = h2v;   // store ack never drained
        }
        if (half == 0 && n + 1 < 512) s_gp[g] = gp_w;  // publish t=n+1 x-gates
        gp_w = gp_l; gp_l = gp_n;
        BARRIER_LGKM();
    }
}

// ---------------------------------------------------------------------------
// Kernel 4: lo = LN(GLU(seq) + vsn_out); K,V; q/lo at t=T-1.  (unchanged)
// ---------------------------------------------------------------------------
__global__ __launch_bounds__(256) void tft_lokv_kernel(
    const float* __restrict__ seq, const float* __restrict__ vsn,
    const float* __restrict__ plgw, const float* __restrict__ plgb,
    const float* __restrict__ png,  const float* __restrict__ pnb,
    const float* __restrict__ qkvw, const float* __restrict__ qkvb,
    float* __restrict__ kbuf, float* __restrict__ vbuf,
    float* __restrict__ qlast, float* __restrict__ lolast)
{
    __shared__ __align__(16) float s_pw[64*128];
    __shared__ __align__(16) float s_qw[64*192];
    __shared__ __align__(16) float s_pb[128];
    __shared__ __align__(16) float s_png[64];
    __shared__ __align__(16) float s_pnb[64];
    __shared__ __align__(16) float s_qb[192];
    __shared__ __align__(16) float s_row[4][64];
    __shared__ __align__(16) float s_lo[4][64];

    const int tid  = threadIdx.x;
    const int lane = tid & 63;
    const int wid  = tid >> 6;

    #pragma unroll
    for (int i = 0; i < 8; i++)
        ((float4*)s_pw)[tid + i*256] = *(const float4*)(plgw + (tid + i*256)*4);
    #pragma unroll
    for (int i = 0; i < 12; i++)
        ((float4*)s_qw)[tid + i*256] = *(const float4*)(qkvw + (tid + i*256)*4);
    if (tid < 128) s_pb[tid] = plgb[tid];
    if (tid < 64){ s_png[tid] = png[tid]; s_pnb[tid] = pnb[tid]; }
    if (tid < 192) s_qb[tid] = qkvb[tid];
    __syncthreads();

    for (int it = 0; it < 16; it++){
        int mpos = blockIdx.x*64 + wid*16 + it;
        int b = mpos >> 9, t = mpos & 511;
        float sv = seq[mpos*64 + lane];
        float vs = vsn[mpos*64 + lane];
        s_row[wid][lane] = sv;
        __syncthreads();
        float a = s_pb[lane], g = s_pb[64 + lane];
        #pragma unroll 8
        for (int k = 0; k < 64; k++){
            float rv = s_row[wid][k];
            a += rv * s_pw[k*128 + lane];
            g += rv * s_pw[k*128 + 64 + lane];
        }
        float pre = a * sigf(g) + vs;
        float mean = wsum64(pre) * 0.015625f;
        float d = pre - mean;
        float vv = wsum64(d*d) * 0.015625f;
        float lo = d * rsqrtf(vv + 1e-5f) * s_png[lane] + s_pnb[lane];
        s_lo[wid][lane] = lo;
        __syncthreads();
        float ka = s_qb[64 + lane], va = s_qb[128 + lane];
        #pragma unroll 8
        for (int k = 0; k < 64; k++){
            float lv = s_lo[wid][k];
            ka += lv * s_qw[k*192 + 64 + lane];
            va += lv * s_qw[k*192 + 128 + lane];
        }
        int h = lane >> 4, dd = lane & 15;
        kbuf[((b*4 + h)*512 + t)*16 + dd] = ka;
        vbuf[((b*4 + h)*512 + t)*16 + dd] = va;
        if (t == 511){
            float qa = s_qb[lane];
            #pragma unroll 8
            for (int k = 0; k < 64; k++)
                qa += s_lo[wid][k] * s_qw[k*192 + lane];
            qlast[b*64 + lane] = qa;
            lolast[b*64 + lane] = lo;
        }
    }
}

// ---------------------------------------------------------------------------
// Kernel 5: head (attention at t=T-1 + GRNs + out).  (unchanged)
// ---------------------------------------------------------------------------
__global__ __launch_bounds__(256) void tft_head_kernel(
    const float* __restrict__ kbuf, const float* __restrict__ vbuf,
    const float* __restrict__ qlast, const float* __restrict__ lolast,
    const float* __restrict__ aow,  const float* __restrict__ aob,
    const float* __restrict__ pagw, const float* __restrict__ pagb,
    const float* __restrict__ pang, const float* __restrict__ panb,
    const float* __restrict__ ff1w, const float* __restrict__ ff1b,
    const float* __restrict__ ff2w, const float* __restrict__ ff2b,
    const float* __restrict__ fflng, const float* __restrict__ fflnb,
    const float* __restrict__ fng,  const float* __restrict__ fnb,
    const float* __restrict__ outw, const float* __restrict__ outb,
    float* __restrict__ out)
{
    __shared__ __align__(16) float s_q[64];
    __shared__ __align__(16) float s_lo[64];
    __shared__ __align__(16) float s_sc[4*512];
    __shared__ __align__(16) float s_part[4][64];
    __shared__ __align__(16) float s_a[64];
    __shared__ __align__(16) float s_a2[64];
    __shared__ __align__(16) float s_z[128];
    __shared__ __align__(16) float s_at[64];
    __shared__ __align__(16) float s_f1[256];

    const int tid = threadIdx.x;
    const int b   = blockIdx.x;
    if (tid < 64){ s_q[tid] = qlast[b*64 + tid]; s_lo[tid] = lolast[b*64 + tid]; }
    __syncthreads();

    for (int idx = tid; idx < 2048; idx += 256){
        int h = idx >> 9, t = idx & 511;
        const float4* kr = (const float4*)(kbuf + ((b*4 + h)*512 + t)*16);
        const float4* qr = (const float4*)(s_q + h*16);
        float4 k0 = kr[0], k1 = kr[1], k2 = kr[2], k3 = kr[3];
        float4 q0 = qr[0], q1 = qr[1], q2 = qr[2], q3 = qr[3];
        float d = q0.x*k0.x + q0.y*k0.y + q0.z*k0.z + q0.w*k0.w
                + q1.x*k1.x + q1.y*k1.y + q1.z*k1.z + q1.w*k1.w
                + q2.x*k2.x + q2.y*k2.y + q2.z*k2.z + q2.w*k2.w
                + q3.x*k3.x + q3.y*k3.y + q3.z*k3.z + q3.w*k3.w;
        s_sc[idx] = d * 0.25f;
    }
    __syncthreads();
    {
        int h = tid >> 6, lane = tid & 63;
        float v[8];
        float mx = -1e30f;
        #pragma unroll
        for (int j = 0; j < 8; j++){ v[j] = s_sc[h*512 + lane + j*64]; mx = fmaxf(mx, v[j]); }
        mx = wmax64(mx);
        float sum = 0.f;
        #pragma unroll
        for (int j = 0; j < 8; j++){ v[j] = __expf(v[j] - mx); sum += v[j]; }
        sum = wsum64(sum);
        float inv = 1.f / sum;
        #pragma unroll
        for (int j = 0; j < 8; j++) s_sc[h*512 + lane + j*64] = v[j] * inv;
    }
    __syncthreads();
    {
        int j = tid & 63, part = tid >> 6;
        int h = j >> 4, dd = j & 15;
        float pa = 0.f;
        for (int t = part*128; t < (part+1)*128; t++)
            pa += s_sc[h*512 + t] * vbuf[((b*4 + h)*512 + t)*16 + dd];
        s_part[part][j] = pa;
    }
    __syncthreads();
    if (tid < 64) s_a[tid] = s_part[0][tid] + s_part[1][tid] + s_part[2][tid] + s_part[3][tid];
    __syncthreads();
    if (tid < 64){
        float o = aob[tid];
        #pragma unroll 8
        for (int k = 0; k < 64; k++) o += s_a[k] * aow[k*64 + tid];
        s_a2[tid] = o;
    }
    __syncthreads();
    if (tid < 128){
        float z = pagb[tid];
        #pragma unroll 8
        for (int k = 0; k < 64; k++) z += s_a2[k] * pagw[k*128 + tid];
        s_z[tid] = z;
    }
    __syncthreads();
    if (tid < 64){
        float pre = s_z[tid] * sigf(s_z[64 + tid]) + s_lo[tid];
        float mean = wsum64(pre) * 0.015625f;
        float d = pre - mean;
        float vv = wsum64(d*d) * 0.015625f;
        s_at[tid] = d * rsqrtf(vv + 1e-5f) * pang[tid] + panb[tid];
    }
    __syncthreads();
    {
        float hv = ff1b[tid];
        #pragma unroll 8
        for (int k = 0; k < 64; k++) hv += s_at[k] * ff1w[k*256 + tid];
        s_f1[tid] = eluf(hv);
    }
    __syncthreads();
    if (tid < 128){
        float z = ff2b[tid];
        #pragma unroll 8
        for (int k = 0; k < 256; k++) z += s_f1[k] * ff2w[k*128 + tid];
        s_z[tid] = z;
    }
    __syncthreads();
    if (tid < 64){
        float pre = s_z[tid] * sigf(s_z[64 + tid]) + s_at[tid];
        float mean = wsum64(pre) * 0.015625f;
        float d = pre - mean;
        float vv = wsum64(d*d) * 0.015625f;
        float ffv = d * rsqrtf(vv + 1e-5f) * fflng[tid] + fflnb[tid];
        float pre2 = ffv + s_at[tid];
        float mean2 = wsum64(pre2) * 0.015625f;
        float d2 = pre2 - mean2;
        float v2 = wsum64(d2*d2) * 0.015625f;
        float f2 = d2 * rsqrtf(v2 + 1e-5f) * fng[tid] + fnb[tid];
        float p = wsum64(f2 * outw[tid]);
        if (tid == 0) out[b] = p + outb[0];
    }
}

// ---------------------------------------------------------------------------
extern "C" void kernel_launch(void* const* d_in, const int* in_sizes, int n_in,
                              void* d_out, int out_size, void* d_ws, size_t ws_size,
                              hipStream_t stream)
{
    const float* x     = (const float*)d_in[0];
    const float* ip_w  = (const float*)d_in[1];
    const float* ip_b  = (const float*)d_in[2];
    const float* vfc1w = (const float*)d_in[3];
    const float* vfc1b = (const float*)d_in[4];
    const float* vfc2w = (const float*)d_in[5];
    const float* vfc2b = (const float*)d_in[6];
    const float* vlng  = (const float*)d_in[7];
    const float* vlnb  = (const float*)d_in[8];
    const float* sfc1w = (const float*)d_in[9];
    const float* sfc1b = (const float*)d_in[10];
    const float* sfc2w = (const float*)d_in[11];
    const float* sfc2b = (const float*)d_in[12];
    const float* sskw  = (const float*)d_in[13];
    const float* sskb  = (const float*)d_in[14];
    const float* slng  = (const float*)d_in[15];
    const float* slnb  = (const float*)d_in[16];
    const float* lwih  = (const float*)d_in[17];
    const float* lwhh  = (const float*)d_in[18];
    const float* lb    = (const float*)d_in[19];
    const float* plgw  = (const float*)d_in[20];
    const float* plgb  = (const float*)d_in[21];
    const float* plng  = (const float*)d_in[22];
    const float* plnb  = (const float*)d_in[23];
    const float* qkvw  = (const float*)d_in[24];
    const float* qkvb  = (const float*)d_in[25];
    const float* aow   = (const float*)d_in[26];
    const float* aob   = (const float*)d_in[27];
    const float* pagw  = (const float*)d_in[28];
    const float* pagb  = (const float*)d_in[29];
    const float* pang  = (const float*)d_in[30];
    const float* panb  = (const float*)d_in[31];
    const float* ff1w  = (const float*)d_in[32];
    const float* ff1b  = (const float*)d_in[33];
    const float* ff2w  = (const float*)d_in[34];
    const float* ff2b  = (const float*)d_in[35];
    const float* fflng = (const float*)d_in[36];
    const float* fflnb = (const float*)d_in[37];
    const float* fng   = (const float*)d_in[38];
    const float* fnb   = (const float*)d_in[39];
    const float* outw  = (const float*)d_in[40];
    const float* outb  = (const float*)d_in[41];

    float* ws      = (float*)d_ws;
    float* vsn_out = ws;                    // 16384*64    = 1,048,576 f
    float* seq     = ws + 1048576;          // 16384*64    = 1,048,576 f
    float* gpre    = ws + 2*1048576;        // 16384*256   = 4,194,304 f
    float* kbuf    = ws + 6*1048576;        // 32*4*512*16 = 1,048,576 f
    float* vbuf    = ws + 7*1048576;        // 1,048,576 f
    float* qlast   = ws + 8*1048576;        // 2048 f
    float* lolast  = qlast + 2048;          // 2048 f
    float* outp    = (float*)d_out;

    tft_vsn_kernel<<<256, 512, 0, stream>>>(x, ip_w, ip_b, vfc1w, vfc1b, vfc2w, vfc2b,
                                            vlng, vlnb, sfc1w, sfc1b, sfc2w, sfc2b,
                                            sskw, sskb, slng, slnb, vsn_out);
    tft_xgates_kernel<<<1024, 256, 0, stream>>>(vsn_out, lwih, lb, gpre);
    tft_lstm_kernel<<<32, 512, 0, stream>>>(lwih, lwhh, lb, gpre, seq);
    tft_lokv_kernel<<<256, 256, 0, stream>>>(seq, vsn_out, plgw, plgb, plng, plnb,
                                             qkvw, qkvb, kbuf, vbuf, qlast, lolast);
    tft_head_kernel<<<32, 256, 0, stream>>>(kbuf, vbuf, qlast, lolast, aow, aob,
                                            pagw, pagb, pang, panb, ff1w, ff1b,
                                            ff2w, ff2b, fflng, fflnb, fng, fnb,
                                            outw, outb, outp);
}